// Round 5
// baseline (14932.809 us; speedup 1.0000x reference)
//
#include <hip/hip_runtime.h>

#define B_ 64
#define N_ 512

typedef __attribute__((ext_vector_type(8))) short bf8_t;   // 8 bf16 (4 VGPRs)
typedef __attribute__((ext_vector_type(4))) float f4_t;    // MFMA accumulator

#define MFMA(a, b, c) __builtin_amdgcn_mfma_f32_16x16x32_bf16(a, b, c, 0, 0, 0)

__device__ __forceinline__ ushort f2bf(float x) {
  union { float f; unsigned u; } v; v.f = x;
  unsigned r = v.u + 0x7FFFu + ((v.u >> 16) & 1u);   // RNE
  return (ushort)(r >> 16);
}
__device__ __forceinline__ float bf2f(ushort h) {
  union { unsigned u; float f; } v; v.u = ((unsigned)h) << 16;
  return v.f;
}

__device__ __forceinline__ void gld16(const ushort* g, ushort* l) {
  __builtin_amdgcn_global_load_lds(
      (const __attribute__((address_space(1))) unsigned int*)(uintptr_t)g,
      (__attribute__((address_space(3))) unsigned int*)(uintptr_t)l,
      16, 0, 0);
}

// XOR swizzle (BK=32: 4x 16B slots/row; (r>>1)&3 spread → 2-way = free)
__device__ __forceinline__ int swz32(int r) { return (r >> 1) & 3; }

// Stage one (ROWS x 32) bf16 tile into LDS, 16B/lane, source pre-swizzled.
template <int ROWS, int THREADS>
__device__ __forceinline__ void stage_tile2(const ushort* g, int lda, int k0,
                                            ushort* l, int tid) {
  constexpr int RT = (ROWS * 32) / (THREADS * 8);
#pragma unroll
  for (int q = 0; q < RT; ++q) {
    int e  = q * THREADS * 8 + tid * 8;
    int r  = e >> 5;
    int c8 = (e >> 3) & 3;
    int g8 = c8 ^ swz32(r);
    gld16(g + (size_t)r * lda + k0 + g8 * 8, l + e);
  }
}

// ---------------------------------------------------------------------------
// Split-bf16 GEMM core: C[m][n] = sum_k A[m][k]*B[n][k], both K-contiguous.
// BM x BN tile, BK=32, double-buffered LDS via global_load_lds,
// 3-term MFMA (AhBh + AhBl + AlBh). Wave tile 64x64 (4x4 frags), WMv x WNv.
// ---------------------------------------------------------------------------
template <int BM, int BN, int WMv, int WNv, int THREADS>
__device__ __forceinline__ void core_g(
    const ushort* Ah, const ushort* Al, int lda,
    const ushort* Bh, const ushort* Bl, int ldb,
    int K, ushort* lds, f4_t acc[4][4]) {
  constexpr int AHo = 0, ALo = BM * 32, BHo = 2 * BM * 32, BLo = (2 * BM + BN) * 32;
  constexpr int SSZ = (2 * BM + 2 * BN) * 32;
  const int tid = threadIdx.x, lane = tid & 63, wave = tid >> 6;
  const int lr = lane & 15, kq = lane >> 4;
  const int wm = wave / WNv, wn = wave % WNv;

  auto stage = [&](int buf, int k0) {
    ushort* lb = lds + buf * SSZ;
    stage_tile2<BM, THREADS>(Ah, lda, k0, lb + AHo, tid);
    stage_tile2<BM, THREADS>(Al, lda, k0, lb + ALo, tid);
    stage_tile2<BN, THREADS>(Bh, ldb, k0, lb + BHo, tid);
    stage_tile2<BN, THREADS>(Bl, ldb, k0, lb + BLo, tid);
  };

  const int nc = K >> 5;
  stage(0, 0);
  int buf = 0;
  for (int c = 0; c < nc; ++c) {
    __syncthreads();
    if (c + 1 < nc) stage(buf ^ 1, (c + 1) << 5);
    const ushort* lb = lds + buf * SSZ;
    bf8_t ah[4], al[4], bh[4], bl[4];
#pragma unroll
    for (int i = 0; i < 4; ++i) {
      int r = wm * 64 + 16 * i + lr;
      int c8 = kq ^ swz32(r);
      ah[i] = *(const bf8_t*)(lb + AHo + r * 32 + c8 * 8);
      al[i] = *(const bf8_t*)(lb + ALo + r * 32 + c8 * 8);
    }
#pragma unroll
    for (int j = 0; j < 4; ++j) {
      int r = wn * 64 + 16 * j + lr;
      int c8 = kq ^ swz32(r);
      bh[j] = *(const bf8_t*)(lb + BHo + r * 32 + c8 * 8);
      bl[j] = *(const bf8_t*)(lb + BLo + r * 32 + c8 * 8);
    }
#pragma unroll
    for (int i = 0; i < 4; ++i)
#pragma unroll
      for (int j = 0; j < 4; ++j) {
        acc[i][j] = MFMA(ah[i], bh[j], acc[i][j]);
        acc[i][j] = MFMA(ah[i], bl[j], acc[i][j]);
        acc[i][j] = MFMA(al[i], bh[j], acc[i][j]);
      }
    buf ^= 1;
  }
}

// ---------------------------------------------------------------------------
// Prep
// ---------------------------------------------------------------------------
__global__ __launch_bounds__(256) void ssq_k(const float* __restrict__ S,
                                             float* __restrict__ SS) {
  int s = blockIdx.z;
  const float* Ss = S + s * N_ * N_;
  __shared__ float Ta[16][17], Tb[16][17];
  int n = blockIdx.y * 16 + threadIdx.y;
  int m = blockIdx.x * 16 + threadIdx.x;
  float acc = 0.f;
  for (int p0 = 0; p0 < N_; p0 += 16) {
    Ta[threadIdx.y][threadIdx.x] = Ss[n * N_ + p0 + threadIdx.x];
    Tb[threadIdx.y][threadIdx.x] = Ss[(p0 + threadIdx.y) * N_ + m];
    __syncthreads();
#pragma unroll
    for (int pp = 0; pp < 16; ++pp)
      acc = fmaf(Ta[threadIdx.y][pp], Tb[pp][threadIdx.x], acc);
    __syncthreads();
  }
  SS[((size_t)s * N_ + n) * N_ + m] = acc;
}

// Bcat[n][k], k = seg*512+m, segs [S0, S0^2, S1, S1^2], split hi/lo
__global__ __launch_bounds__(256) void bcat_k(const float* __restrict__ S,
                                              const float* __restrict__ SS,
                                              ushort* __restrict__ Bh,
                                              ushort* __restrict__ Bl) {
  int idx = blockIdx.x * 256 + threadIdx.x;
  if (idx >= 512 * 2048) return;
  int k = idx & 2047, n = idx >> 11;
  int seg = k >> 9, m = k & 511;
  float v;
  if (seg == 0)      v = S[(size_t)n * 512 + m];
  else if (seg == 1) v = SS[(size_t)n * 512 + m];
  else if (seg == 2) v = S[(size_t)(512 + n) * 512 + m];
  else               v = SS[(size_t)(512 + n) * 512 + m];
  ushort hh = f2bf(v);
  Bh[idx] = hh; Bl[idx] = f2bf(v - bf2f(hh));
}

// Wt[i = t*Dout + d][c] (128-wide rows) from W[(t*C+c)*Dout + d]; zeros outside
__global__ __launch_bounds__(256) void wprep2_k(const float* __restrict__ W,
                                                ushort* __restrict__ Wh,
                                                ushort* __restrict__ Wl,
                                                int C, int Dout, int Mt) {
  int idx = blockIdx.x * 256 + threadIdx.x;
  if (idx >= Mt * 128) return;
  int c = idx & 127, i = idx >> 7;
  int t = i / Dout, d = i % Dout;
  float v = (c < C && t < 5) ? W[(size_t)(t * C + c) * Dout + d] : 0.f;
  ushort hh = f2bf(v);
  Wh[idx] = hh; Wl[idx] = f2bf(v - bf2f(hh));
}

// ---------------------------------------------------------------------------
// Pack zT[(b,n)][c] = [x | h | 0-pad], split hi/lo.
// ---------------------------------------------------------------------------
__global__ __launch_bounds__(256) void packzT_k(const float* __restrict__ xsrc,
                                                int xmode, int t, int Cx, int C,
                                                const float* __restrict__ h,
                                                ushort* __restrict__ Zh,
                                                ushort* __restrict__ Zl) {
  int jg = blockIdx.x * 256 + threadIdx.x;   // b*512 + n
  int b = jg >> 9, n = jg & 511;
  for (int c0 = 0; c0 < 128; c0 += 8) {
    bf8_t vh, vl;
#pragma unroll
    for (int q = 0; q < 8; ++q) {
      int c = c0 + q;
      float v;
      if (c < Cx) v = (xmode == 0) ? xsrc[((size_t)(b * Cx + c) * 512 + n) * 12 + t]
                                   : xsrc[(size_t)(b * Cx + c) * 512 + n];
      else if (c < C) v = h[((size_t)b * 64 + (c - Cx)) * 512 + n];
      else v = 0.f;
      ushort hh = f2bf(v);
      vh[q] = (short)hh;
      vl[q] = (short)f2bf(v - bf2f(hh));
    }
    *(bf8_t*)(Zh + (size_t)jg * 128 + c0) = vh;
    *(bf8_t*)(Zl + (size_t)jg * 128 + c0) = vl;
  }
}

// ---------------------------------------------------------------------------
// Step 1: G = Wt * zT^T.  A = Wt (Mt x 128-ld), B = zT (32768 x 128-ld), K=K1.
// Flat G layout: G[(b*Dr + d)][t*512 + m], lda 2560.
// MODE 0 (gate, Dr=128): ii -> t = ii>>7, d = ii&127
// MODE 1 (cand, Dr=64):  ii -> t = ii>>6, d = ii&63
// ---------------------------------------------------------------------------
template <int MODE>
__global__ __launch_bounds__(256) void g1_k(const ushort* __restrict__ Wh,
                                            const ushort* __restrict__ Wl,
                                            const ushort* __restrict__ Zh,
                                            const ushort* __restrict__ Zl,
                                            ushort* __restrict__ Gh,
                                            ushort* __restrict__ Gl,
                                            int K, int Mlimit) {
  __shared__ __attribute__((aligned(16))) ushort lds[2 * 4 * 128 * 32];
  int tid = threadIdx.x, lane = tid & 63, wave = tid >> 6;
  int wm = wave >> 1, wn = wave & 1, lr = lane & 15, kq = lane >> 4;
  int nt = blockIdx.x, mt = blockIdx.y;
  f4_t acc[4][4] = {};
  core_g<128, 128, 2, 2, 256>(Wh + (size_t)mt * 128 * 128, Wl + (size_t)mt * 128 * 128, 128,
                              Zh + (size_t)nt * 128 * 128, Zl + (size_t)nt * 128 * 128, 128,
                              K, lds, acc);
#pragma unroll
  for (int i = 0; i < 4; ++i) {
    int ii0 = mt * 128 + wm * 64 + 16 * i + kq * 4;
    if (ii0 >= Mlimit) continue;
#pragma unroll
    for (int j = 0; j < 4; ++j) {
      int jg = nt * 128 + wn * 64 + 16 * j + lr;
      int b = jg >> 9, m = jg & 511;
      f4_t v = acc[i][j];
#pragma unroll
      for (int r = 0; r < 4; ++r) {
        int ii = ii0 + r;
        if (ii >= Mlimit) break;
        int t, R;
        if (MODE == 0) { t = ii >> 7; R = b * 128 + (ii & 127); }
        else           { t = ii >> 6; R = b * 64 + (ii & 63); }
        size_t addr = (size_t)R * 2560 + t * 512 + m;
        ushort hh = f2bf(v[r]);
        Gh[addr] = hh; Gl[addr] = f2bf(v[r] - bf2f(hh));
      }
    }
  }
}

// ---------------------------------------------------------------------------
// Step 2: RU[R][n] = sum_{k=0..2047} G[R][512+k] * Bcat[n][k]  (+ G[R][n] id term)
// BM=64 x BN=128, 128 threads (2 waves). grid (mt, nt).
// MODE 0 (gate): sigmoid; d<64 -> r*h into zT; d>=64 -> u into U.
// MODE 1 (cand): h = u*h + (1-u)*tanh(.)
// ---------------------------------------------------------------------------
template <int MODE>
__global__ __launch_bounds__(128) void ru_k(const ushort* __restrict__ Gh,
                                            const ushort* __restrict__ Gl,
                                            const ushort* __restrict__ Bch,
                                            const ushort* __restrict__ Bcl,
                                            const float* __restrict__ bias,
                                            const float* __restrict__ hin,
                                            float* __restrict__ U,
                                            ushort* __restrict__ Zh,
                                            ushort* __restrict__ Zl,
                                            float* __restrict__ hout, int Cx) {
  __shared__ __attribute__((aligned(16))) ushort lds[2 * (2 * 64 + 2 * 128) * 32];
  int tid = threadIdx.x, lane = tid & 63, wave = tid >> 6;
  int lr = lane & 15, kq = lane >> 4;
  int wn = wave;                       // WMv=1, WNv=2
  int mt = blockIdx.x, nt = blockIdx.y;
  f4_t acc[4][4] = {};
  core_g<64, 128, 1, 2, 128>(Gh + (size_t)mt * 64 * 2560 + 512,
                             Gl + (size_t)mt * 64 * 2560 + 512, 2560,
                             Bch + (size_t)nt * 128 * 2048,
                             Bcl + (size_t)nt * 128 * 2048, 2048,
                             2048, lds, acc);
#pragma unroll
  for (int i = 0; i < 4; ++i) {
    int row0 = 16 * i + kq * 4;
#pragma unroll
    for (int j = 0; j < 4; ++j) {
      int n = nt * 128 + wn * 64 + 16 * j + lr;
      f4_t v = acc[i][j];
#pragma unroll
      for (int r = 0; r < 4; ++r) {
        int R = mt * 64 + row0 + r;
        size_t g0 = (size_t)R * 2560 + n;
        float s0 = v[r] + bf2f(Gh[g0]) + bf2f(Gl[g0]);
        if (MODE == 0) {
          int d = R & 127, b = R >> 7;
          float s = 1.f / (1.f + expf(-(s0 + bias[d])));
          if (d < 64) {
            float rh = s * hin[((size_t)b * 64 + d) * 512 + n];
            ushort hh = f2bf(rh);
            size_t zi = ((size_t)b * 512 + n) * 128 + Cx + d;
            Zh[zi] = hh; Zl[zi] = f2bf(rh - bf2f(hh));
          } else {
            U[((size_t)b * 64 + (d - 64)) * 512 + n] = s;
          }
        } else {
          int d = R & 63;
          float ct = tanhf(s0 + bias[d]);
          size_t ix = (size_t)R * 512 + n;
          float u = U[ix];
          hout[ix] = u * hout[ix] + (1.f - u) * ct;
        }
      }
    }
  }
}

__global__ __launch_bounds__(256) void proj_out_k(const float* __restrict__ h1,
                                                  const float* __restrict__ pw,
                                                  const float* __restrict__ pb,
                                                  float* __restrict__ ybuf,
                                                  float* __restrict__ out, int k) {
  int idx = blockIdx.x * blockDim.x + threadIdx.x;
  if (idx >= B_ * N_) return;
  float s = pb[0];
#pragma unroll
  for (int j = 0; j < 64; ++j)
    s = fmaf(pw[j], h1[(size_t)((idx >> 9) * 64 + j) * 512 + (idx & 511)], s);
  ybuf[idx] = s;
  out[(size_t)idx * 12 + k] = s;
}

extern "C" void kernel_launch(void* const* d_in, const int* in_sizes, int n_in,
                              void* d_out, int out_size, void* d_ws, size_t ws_size,
                              hipStream_t stream) {
  const float* inputs   = (const float*)d_in[0];
  const float* supports = (const float*)d_in[1];
  const float* Wg[4] = { (const float*)d_in[2],  (const float*)d_in[6],
                         (const float*)d_in[10], (const float*)d_in[14] };
  const float* Bg[4] = { (const float*)d_in[3],  (const float*)d_in[7],
                         (const float*)d_in[11], (const float*)d_in[15] };
  const float* Wc[4] = { (const float*)d_in[4],  (const float*)d_in[8],
                         (const float*)d_in[12], (const float*)d_in[16] };
  const float* Bc[4] = { (const float*)d_in[5],  (const float*)d_in[9],
                         (const float*)d_in[13], (const float*)d_in[17] };
  const float* proj_w = (const float*)d_in[18];
  const float* proj_b = (const float*)d_in[19];
  float* out = (float*)d_out;

  char* p = (char*)d_ws;
  auto carve = [&](size_t bytes) { void* q = p; p += (bytes + 255) & ~(size_t)255; return q; };
  ushort* Bch = (ushort*)carve((size_t)512 * 2048 * 2);
  ushort* Bcl = (ushort*)carve((size_t)512 * 2048 * 2);
  ushort* zTh = (ushort*)carve((size_t)32768 * 128 * 2);
  ushort* zTl = (ushort*)carve((size_t)32768 * 128 * 2);
  ushort* Gh  = (ushort*)carve((size_t)8192 * 2560 * 2);   // 42 MB
  ushort* Gl  = (ushort*)carve((size_t)8192 * 2560 * 2);
  float*  U   = (float*)carve((size_t)4096 * 512 * 4);
  float*  h0  = (float*)carve((size_t)4096 * 512 * 4);
  float*  h1  = (float*)carve((size_t)4096 * 512 * 4);
  float*  ybuf = (float*)carve((size_t)B_ * N_ * 4);
  ushort* Wgh[4]; ushort* Wgl[4]; ushort* Wch[4]; ushort* Wcl[4];
  for (int c = 0; c < 4; ++c) {
    Wgh[c] = (ushort*)carve((size_t)640 * 128 * 2);
    Wgl[c] = (ushort*)carve((size_t)640 * 128 * 2);
    Wch[c] = (ushort*)carve((size_t)384 * 128 * 2);
    Wcl[c] = (ushort*)carve((size_t)384 * 128 * 2);
  }
  float* SSbuf = (float*)U;   // overlay: SS only needed during prep

  hipMemsetAsync(h0, 0, (size_t)4096 * 512 * 4, stream);
  hipMemsetAsync(h1, 0, (size_t)4096 * 512 * 4, stream);
  hipMemsetAsync(ybuf, 0, (size_t)B_ * N_ * 4, stream);

  ssq_k<<<dim3(32, 32, 2), dim3(16, 16), 0, stream>>>(supports, SSbuf);
  bcat_k<<<(512 * 2048 + 255) / 256, 256, 0, stream>>>(supports, SSbuf, Bch, Bcl);
  const int Cs[4] = { 66, 128, 65, 128 };
  for (int c = 0; c < 4; ++c) {
    wprep2_k<<<(640 * 128 + 255) / 256, 256, 0, stream>>>(Wg[c], Wgh[c], Wgl[c], Cs[c], 128, 640);
    wprep2_k<<<(384 * 128 + 255) / 256, 256, 0, stream>>>(Wc[c], Wch[c], Wcl[c], Cs[c], 64, 384);
  }

  auto cell = [&](int ci, int Cx, const float* x, int xmode, int t, float* h) {
    int C = Cx + 64;
    int K1 = (C + 31) & ~31;   // 96 or 128
    packzT_k<<<128, 256, 0, stream>>>(x, xmode, t, Cx, C, h, zTh, zTl);
    g1_k<0><<<dim3(256, 5), 256, 0, stream>>>(Wgh[ci], Wgl[ci], zTh, zTl, Gh, Gl, K1, 640);
    ru_k<0><<<dim3(128, 4), 128, 0, stream>>>(Gh, Gl, Bch, Bcl, Bg[ci], h, U, zTh, zTl,
                                              nullptr, Cx);
    g1_k<1><<<dim3(256, 3), 256, 0, stream>>>(Wch[ci], Wcl[ci], zTh, zTl, Gh, Gl, K1, 320);
    ru_k<1><<<dim3(64, 4), 128, 0, stream>>>(Gh, Gl, Bch, Bcl, Bc[ci], nullptr, U,
                                             nullptr, nullptr, h, Cx);
  };

  for (int t = 0; t < 12; ++t) {
    cell(0, 2, inputs, 0, t, h0);
    cell(1, 64, h0, 1, 0, h1);
  }
  for (int k = 0; k < 12; ++k) {
    cell(2, 1, ybuf, 1, 0, h0);
    cell(3, 64, h0, 1, 0, h1);
    proj_out_k<<<(B_ * N_ + 255) / 256, 256, 0, stream>>>(h1, proj_w, proj_b, ybuf, out, k);
  }
}

// Round 7
// 11462.735 us; speedup vs baseline: 1.3027x; 1.3027x over previous
//
#include <hip/hip_runtime.h>

#define B_ 64
#define N_ 512

typedef __attribute__((ext_vector_type(8))) short bf8_t;   // 8 bf16 (4 VGPRs)
typedef __attribute__((ext_vector_type(4))) float f4_t;    // MFMA accumulator

#define MFMA(a, b, c) __builtin_amdgcn_mfma_f32_16x16x32_bf16(a, b, c, 0, 0, 0)

__device__ __forceinline__ ushort f2bf(float x) {
  union { float f; unsigned u; } v; v.f = x;
  unsigned r = v.u + 0x7FFFu + ((v.u >> 16) & 1u);   // RNE
  return (ushort)(r >> 16);
}
__device__ __forceinline__ float bf2f(ushort h) {
  union { unsigned u; float f; } v; v.u = ((unsigned)h) << 16;
  return v.f;
}

__device__ __forceinline__ void gld16(const ushort* g, ushort* l) {
  __builtin_amdgcn_global_load_lds(
      (const __attribute__((address_space(1))) unsigned int*)(uintptr_t)g,
      (__attribute__((address_space(3))) unsigned int*)(uintptr_t)l,
      16, 0, 0);
}

// XOR swizzle (BK=32: 4x 16B slots/row; (r>>1)&3 spread → 2-way = free)
__device__ __forceinline__ int swz32(int r) { return (r >> 1) & 3; }

template <int ROWS, int THREADS>
__device__ __forceinline__ void stage_tile2(const ushort* g, int lda, int k0,
                                            ushort* l, int tid) {
  constexpr int RT = (ROWS * 32) / (THREADS * 8);
#pragma unroll
  for (int q = 0; q < RT; ++q) {
    int e  = q * THREADS * 8 + tid * 8;
    int r  = e >> 5;
    int c8 = (e >> 3) & 3;
    int g8 = c8 ^ swz32(r);
    gld16(g + (size_t)r * lda + k0 + g8 * 8, l + e);
  }
}

// ---------------------------------------------------------------------------
// Split-bf16 GEMM core: C[m][n] = sum_k A[m][k]*B[n][k], both K-contiguous.
// 128x128 tile, BK=32, double-buffered 64KB LDS, 3-term MFMA, 2x2 waves.
// ---------------------------------------------------------------------------
__device__ __forceinline__ void core128(
    const ushort* Ah, const ushort* Al, int lda,
    const ushort* Bh, const ushort* Bl, int ldb,
    int K, ushort* lds, f4_t acc[4][4]) {
  constexpr int TILE = 128 * 32;
  constexpr int SSZ  = 4 * TILE;
  const int tid = threadIdx.x, lane = tid & 63, wave = tid >> 6;
  const int lr = lane & 15, kq = lane >> 4;
  const int wm = wave >> 1, wn = wave & 1;

  auto stage = [&](int buf, int k0) {
    ushort* lb = lds + buf * SSZ;
    stage_tile2<128, 256>(Ah, lda, k0, lb, tid);
    stage_tile2<128, 256>(Al, lda, k0, lb + TILE, tid);
    stage_tile2<128, 256>(Bh, ldb, k0, lb + 2 * TILE, tid);
    stage_tile2<128, 256>(Bl, ldb, k0, lb + 3 * TILE, tid);
  };

  const int nc = K >> 5;
  stage(0, 0);
  int buf = 0;
  for (int c = 0; c < nc; ++c) {
    __syncthreads();
    if (c + 1 < nc) stage(buf ^ 1, (c + 1) << 5);
    const ushort* lb = lds + buf * SSZ;
    bf8_t ah[4], al[4], bh[4], bl[4];
#pragma unroll
    for (int i = 0; i < 4; ++i) {
      int r = wm * 64 + 16 * i + lr;
      int c8 = kq ^ swz32(r);
      ah[i] = *(const bf8_t*)(lb + r * 32 + c8 * 8);
      al[i] = *(const bf8_t*)(lb + TILE + r * 32 + c8 * 8);
    }
#pragma unroll
    for (int j = 0; j < 4; ++j) {
      int r = wn * 64 + 16 * j + lr;
      int c8 = kq ^ swz32(r);
      bh[j] = *(const bf8_t*)(lb + 2 * TILE + r * 32 + c8 * 8);
      bl[j] = *(const bf8_t*)(lb + 3 * TILE + r * 32 + c8 * 8);
    }
#pragma unroll
    for (int i = 0; i < 4; ++i)
#pragma unroll
      for (int j = 0; j < 4; ++j) {
        acc[i][j] = MFMA(ah[i], bh[j], acc[i][j]);
        acc[i][j] = MFMA(ah[i], bl[j], acc[i][j]);
        acc[i][j] = MFMA(al[i], bh[j], acc[i][j]);
      }
    buf ^= 1;
  }
}

// ---------------------------------------------------------------------------
// Prep
// ---------------------------------------------------------------------------
__global__ __launch_bounds__(256) void ssq_k(const float* __restrict__ S,
                                             float* __restrict__ SS) {
  int s = blockIdx.z;
  const float* Ss = S + s * N_ * N_;
  __shared__ float Ta[16][17], Tb[16][17];
  int n = blockIdx.y * 16 + threadIdx.y;
  int m = blockIdx.x * 16 + threadIdx.x;
  float acc = 0.f;
  for (int p0 = 0; p0 < N_; p0 += 16) {
    Ta[threadIdx.y][threadIdx.x] = Ss[n * N_ + p0 + threadIdx.x];
    Tb[threadIdx.y][threadIdx.x] = Ss[(p0 + threadIdx.y) * N_ + m];
    __syncthreads();
#pragma unroll
    for (int pp = 0; pp < 16; ++pp)
      acc = fmaf(Ta[threadIdx.y][pp], Tb[pp][threadIdx.x], acc);
    __syncthreads();
  }
  SS[((size_t)s * N_ + n) * N_ + m] = acc;
}

// Bcat[n][k], k = seg*512+m, segs [S0, S0^2, S1, S1^2], split hi/lo
__global__ __launch_bounds__(256) void bcat_k(const float* __restrict__ S,
                                              const float* __restrict__ SS,
                                              ushort* __restrict__ Bh,
                                              ushort* __restrict__ Bl) {
  int idx = blockIdx.x * 256 + threadIdx.x;
  if (idx >= 512 * 2048) return;
  int k = idx & 2047, n = idx >> 11;
  int seg = k >> 9, m = k & 511;
  float v;
  if (seg == 0)      v = S[(size_t)n * 512 + m];
  else if (seg == 1) v = SS[(size_t)n * 512 + m];
  else if (seg == 2) v = S[(size_t)(512 + n) * 512 + m];
  else               v = SS[(size_t)(512 + n) * 512 + m];
  ushort hh = f2bf(v);
  Bh[idx] = hh; Bl[idx] = f2bf(v - bf2f(hh));
}

// Wt[i = t*Dout + d][c] (128-wide rows) from W[(t*C+c)*Dout + d]; zeros outside
__global__ __launch_bounds__(256) void wprep2_k(const float* __restrict__ W,
                                                ushort* __restrict__ Wh,
                                                ushort* __restrict__ Wl,
                                                int C, int Dout, int Mt) {
  int idx = blockIdx.x * 256 + threadIdx.x;
  if (idx >= Mt * 128) return;
  int c = idx & 127, i = idx >> 7;
  int t = i / Dout, d = i % Dout;
  float v = (c < C && t < 5) ? W[(size_t)(t * C + c) * Dout + d] : 0.f;
  ushort hh = f2bf(v);
  Wh[idx] = hh; Wl[idx] = f2bf(v - bf2f(hh));
}

// ---------------------------------------------------------------------------
// Pack zT[(b,n)][c] = [x | h | 0-pad], split hi/lo. hT is [(b,n)][d].
// xmode 0: inputs gather (t); xmode 1: flat [jg] (ybuf, Cx=1);
// xmode 2: hT-row layout (x = previous layer's h, [(b,n)][d])
// ---------------------------------------------------------------------------
__global__ __launch_bounds__(256) void packzT_k(const float* __restrict__ xsrc,
                                                int xmode, int t, int Cx, int C,
                                                const float* __restrict__ hT,
                                                ushort* __restrict__ Zh,
                                                ushort* __restrict__ Zl) {
  int jg = blockIdx.x * 256 + threadIdx.x;   // b*512 + n
  int b = jg >> 9, n = jg & 511;
  for (int c0 = 0; c0 < 128; c0 += 8) {
    bf8_t vh, vl;
#pragma unroll
    for (int q = 0; q < 8; ++q) {
      int c = c0 + q;
      float v;
      if (c < Cx) {
        if (xmode == 0)      v = xsrc[((size_t)(b * Cx + c) * 512 + n) * 12 + t];
        else if (xmode == 1) v = xsrc[jg];
        else                 v = xsrc[(size_t)jg * 64 + c];
      } else if (c < C) {
        v = hT[(size_t)jg * 64 + (c - Cx)];
      } else {
        v = 0.f;
      }
      ushort hh = f2bf(v);
      vh[q] = (short)hh;
      vl[q] = (short)f2bf(v - bf2f(hh));
    }
    *(bf8_t*)(Zh + (size_t)jg * 128 + c0) = vh;
    *(bf8_t*)(Zl + (size_t)jg * 128 + c0) = vl;
  }
}

// ---------------------------------------------------------------------------
// Step 1: G = Wt * zT^T. A = Wt (Mt x 128), B = zT (32768 x 128), K=K1.
// t=0 rows -> f32 G0T[jg][d] (stride DR); t>=1 -> Gh/Gl[(b*DR+d)*2048+(t-1)*512+m]
// MODE 0: DR=128 (gate); MODE 1: DR=64 (cand)
// ---------------------------------------------------------------------------
template <int MODE>
__global__ __launch_bounds__(256) void g1_k(const ushort* __restrict__ Wh,
                                            const ushort* __restrict__ Wl,
                                            const ushort* __restrict__ Zh,
                                            const ushort* __restrict__ Zl,
                                            ushort* __restrict__ Gh,
                                            ushort* __restrict__ Gl,
                                            float* __restrict__ G0T,
                                            int K, int Mlimit) {
  __shared__ __attribute__((aligned(16))) ushort lds[2 * 4 * 128 * 32];
  constexpr int DR = (MODE == 0) ? 128 : 64;
  int tid = threadIdx.x, lane = tid & 63, wave = tid >> 6;
  int wm = wave >> 1, wn = wave & 1, lr = lane & 15, kq = lane >> 4;
  int nt = blockIdx.x, mt = blockIdx.y;
  f4_t acc[4][4] = {};
  core128(Wh + (size_t)mt * 128 * 128, Wl + (size_t)mt * 128 * 128, 128,
          Zh + (size_t)nt * 128 * 128, Zl + (size_t)nt * 128 * 128, 128,
          K, lds, acc);
#pragma unroll
  for (int i = 0; i < 4; ++i) {
    int ii0 = mt * 128 + wm * 64 + 16 * i + kq * 4;
    if (ii0 >= Mlimit) continue;
#pragma unroll
    for (int j = 0; j < 4; ++j) {
      int jg = nt * 128 + wn * 64 + 16 * j + lr;   // b*512 + m
      int b = jg >> 9, m = jg & 511;
      f4_t v = acc[i][j];
#pragma unroll
      for (int r = 0; r < 4; ++r) {
        int ii = ii0 + r;
        if (ii >= Mlimit) break;
        int t = ii / DR, d = ii % DR;
        if (t == 0) {
          G0T[(size_t)jg * DR + d] = v[r];
        } else {
          size_t addr = ((size_t)(b * DR + d)) * 2048 + (size_t)(t - 1) * 512 + m;
          ushort hh = f2bf(v[r]);
          Gh[addr] = hh; Gl[addr] = f2bf(v[r] - bf2f(hh));
        }
      }
    }
  }
}

// ---------------------------------------------------------------------------
// Gate diffusion (transposed): C[n][R] = Bcat * G^T, K=2048.
// grid (nt=64 over R, mt=4 over n). Epilogue: sigmoid(+G0T+bg);
// d<64 -> r*h into zT; d>=64 -> u into U ([(b,n)][d] layouts).
// ---------------------------------------------------------------------------
__global__ __launch_bounds__(256) void ru1_k(const ushort* __restrict__ Gh,
                                             const ushort* __restrict__ Gl,
                                             const ushort* __restrict__ Bch,
                                             const ushort* __restrict__ Bcl,
                                             const float* __restrict__ G0T,
                                             const float* __restrict__ bg,
                                             const float* __restrict__ hT,
                                             float* __restrict__ U,
                                             ushort* __restrict__ Zh,
                                             ushort* __restrict__ Zl, int Cx) {
  __shared__ __attribute__((aligned(16))) ushort lds[2 * 4 * 128 * 32];
  int tid = threadIdx.x, lane = tid & 63, wave = tid >> 6;
  int wm = wave >> 1, wn = wave & 1, lr = lane & 15, kq = lane >> 4;
  int nt = blockIdx.x, mt = blockIdx.y;
  f4_t acc[4][4] = {};
  core128(Bch + (size_t)mt * 128 * 2048, Bcl + (size_t)mt * 128 * 2048, 2048,
          Gh + (size_t)nt * 128 * 2048, Gl + (size_t)nt * 128 * 2048, 2048,
          2048, lds, acc);
#pragma unroll
  for (int i = 0; i < 4; ++i) {
    int n0 = mt * 128 + wm * 64 + 16 * i + kq * 4;
#pragma unroll
    for (int j = 0; j < 4; ++j) {
      int R = nt * 128 + wn * 64 + 16 * j + lr;
      int b = R >> 7, d = R & 127;
      f4_t v = acc[i][j];
#pragma unroll
      for (int r = 0; r < 4; ++r) {
        size_t row = (size_t)b * 512 + n0 + r;
        float s = v[r] + G0T[row * 128 + d] + bg[d];
        s = 1.f / (1.f + expf(-s));
        if (d < 64) {
          float rh = s * hT[row * 64 + d];
          ushort hh = f2bf(rh);
          Zh[row * 128 + Cx + d] = hh;
          Zl[row * 128 + Cx + d] = f2bf(rh - bf2f(hh));
        } else {
          U[row * 64 + (d - 64)] = s;
        }
      }
    }
  }
}

// ---------------------------------------------------------------------------
// Cand diffusion GEMM (transposed, split-K by support):
// grid (nt=32 over R(4096), mt=4 over n, kz=2). P[kz][(b,n)][d] f32 partials.
// ---------------------------------------------------------------------------
__global__ __launch_bounds__(256) void ru2g_k(const ushort* __restrict__ Gh,
                                              const ushort* __restrict__ Gl,
                                              const ushort* __restrict__ Bch,
                                              const ushort* __restrict__ Bcl,
                                              float* __restrict__ P) {
  __shared__ __attribute__((aligned(16))) ushort lds[2 * 4 * 128 * 32];
  int tid = threadIdx.x, lane = tid & 63, wave = tid >> 6;
  int wm = wave >> 1, wn = wave & 1, lr = lane & 15, kq = lane >> 4;
  int nt = blockIdx.x, mt = blockIdx.y, kz = blockIdx.z;
  f4_t acc[4][4] = {};
  core128(Bch + (size_t)mt * 128 * 2048 + kz * 1024,
          Bcl + (size_t)mt * 128 * 2048 + kz * 1024, 2048,
          Gh + (size_t)nt * 128 * 2048 + kz * 1024,
          Gl + (size_t)nt * 128 * 2048 + kz * 1024, 2048,
          1024, lds, acc);
  float* Pz = P + (size_t)kz * 2097152;
#pragma unroll
  for (int i = 0; i < 4; ++i) {
    int n0 = mt * 128 + wm * 64 + 16 * i + kq * 4;
#pragma unroll
    for (int j = 0; j < 4; ++j) {
      int R = nt * 128 + wn * 64 + 16 * j + lr;
      int b = R >> 6, d = R & 63;
      f4_t v = acc[i][j];
#pragma unroll
      for (int r = 0; r < 4; ++r) {
        size_t row = (size_t)b * 512 + n0 + r;
        Pz[row * 64 + d] = v[r];
      }
    }
  }
}

// c~ = tanh(P0+P1+G0c+bc); h = u*h + (1-u)*c~   (all [(b,n)][d] contiguous)
__global__ __launch_bounds__(256) void ru2f_k(const float* __restrict__ P,
                                              const float* __restrict__ G0c,
                                              const float* __restrict__ bc,
                                              const float* __restrict__ U,
                                              float* __restrict__ hT) {
  int idx = blockIdx.x * 256 + threadIdx.x;
  if (idx >= 2097152) return;
  float ct = tanhf(P[idx] + P[idx + 2097152] + G0c[idx] + bc[idx & 63]);
  float u = U[idx];
  hT[idx] = u * hT[idx] + (1.f - u) * ct;
}

__global__ __launch_bounds__(256) void proj_out_k(const float* __restrict__ h1T,
                                                  const float* __restrict__ pw,
                                                  const float* __restrict__ pb,
                                                  float* __restrict__ ybuf,
                                                  float* __restrict__ out, int k) {
  int idx = blockIdx.x * blockDim.x + threadIdx.x;
  if (idx >= B_ * N_) return;
  float s = pb[0];
  const float* hrow = h1T + (size_t)idx * 64;
#pragma unroll
  for (int j = 0; j < 64; ++j)
    s = fmaf(pw[j], hrow[j], s);
  ybuf[idx] = s;
  out[(size_t)idx * 12 + k] = s;
}

extern "C" void kernel_launch(void* const* d_in, const int* in_sizes, int n_in,
                              void* d_out, int out_size, void* d_ws, size_t ws_size,
                              hipStream_t stream) {
  const float* inputs   = (const float*)d_in[0];
  const float* supports = (const float*)d_in[1];
  const float* Wg[4] = { (const float*)d_in[2],  (const float*)d_in[6],
                         (const float*)d_in[10], (const float*)d_in[14] };
  const float* Bg[4] = { (const float*)d_in[3],  (const float*)d_in[7],
                         (const float*)d_in[11], (const float*)d_in[15] };
  const float* Wc[4] = { (const float*)d_in[4],  (const float*)d_in[8],
                         (const float*)d_in[12], (const float*)d_in[16] };
  const float* Bc[4] = { (const float*)d_in[5],  (const float*)d_in[9],
                         (const float*)d_in[13], (const float*)d_in[17] };
  const float* proj_w = (const float*)d_in[18];
  const float* proj_b = (const float*)d_in[19];
  float* out = (float*)d_out;

  char* p = (char*)d_ws;
  auto carve = [&](size_t bytes) { void* q = p; p += (bytes + 255) & ~(size_t)255; return q; };
  ushort* Bch = (ushort*)carve((size_t)512 * 2048 * 2);
  ushort* Bcl = (ushort*)carve((size_t)512 * 2048 * 2);
  ushort* zTh = (ushort*)carve((size_t)32768 * 128 * 2);   // also reused as P (f32 x 4M)
  ushort* zTl = (ushort*)carve((size_t)32768 * 128 * 2);
  ushort* Gh  = (ushort*)carve((size_t)8192 * 2048 * 2);
  ushort* Gl  = (ushort*)carve((size_t)8192 * 2048 * 2);
  float*  G0T = (float*)carve((size_t)32768 * 128 * 4);    // gate G0 (stride128) / cand G0 (stride64)
  float*  U   = (float*)carve((size_t)2097152 * 4);
  float*  h0  = (float*)carve((size_t)2097152 * 4);
  float*  h1  = (float*)carve((size_t)2097152 * 4);
  float*  ybuf = (float*)carve((size_t)B_ * N_ * 4);
  ushort* Wgh[4]; ushort* Wgl[4]; ushort* Wch[4]; ushort* Wcl[4];
  for (int c = 0; c < 4; ++c) {
    Wgh[c] = (ushort*)carve((size_t)640 * 128 * 2);
    Wgl[c] = (ushort*)carve((size_t)640 * 128 * 2);
    Wch[c] = (ushort*)carve((size_t)384 * 128 * 2);
    Wcl[c] = (ushort*)carve((size_t)384 * 128 * 2);
  }
  float* P = (float*)zTh;        // ru2 partials overlay zT (dead after g1c)
  float* SSbuf = (float*)U;      // SS only needed during prep

  hipMemsetAsync(h0, 0, (size_t)2097152 * 4, stream);
  hipMemsetAsync(h1, 0, (size_t)2097152 * 4, stream);
  hipMemsetAsync(ybuf, 0, (size_t)B_ * N_ * 4, stream);

  ssq_k<<<dim3(32, 32, 2), dim3(16, 16), 0, stream>>>(supports, SSbuf);
  bcat_k<<<(512 * 2048 + 255) / 256, 256, 0, stream>>>(supports, SSbuf, Bch, Bcl);
  const int Cs[4] = { 66, 128, 65, 128 };
  for (int c = 0; c < 4; ++c) {
    wprep2_k<<<(640 * 128 + 255) / 256, 256, 0, stream>>>(Wg[c], Wgh[c], Wgl[c], Cs[c], 128, 640);
    wprep2_k<<<(384 * 128 + 255) / 256, 256, 0, stream>>>(Wc[c], Wch[c], Wcl[c], Cs[c], 64, 384);
  }

  auto cell = [&](int ci, int Cx, const float* x, int xmode, int t, float* h) {
    int C = Cx + 64;
    int K1 = (C + 31) & ~31;   // 96 or 128
    packzT_k<<<128, 256, 0, stream>>>(x, xmode, t, Cx, C, h, zTh, zTl);
    g1_k<0><<<dim3(256, 5), 256, 0, stream>>>(Wgh[ci], Wgl[ci], zTh, zTl, Gh, Gl, G0T, K1, 640);
    ru1_k<<<dim3(64, 4), 256, 0, stream>>>(Gh, Gl, Bch, Bcl, G0T, Bg[ci], h, U, zTh, zTl, Cx);
    g1_k<1><<<dim3(256, 3), 256, 0, stream>>>(Wch[ci], Wcl[ci], zTh, zTl, Gh, Gl, G0T, K1, 320);
    ru2g_k<<<dim3(32, 4, 2), 256, 0, stream>>>(Gh, Gl, Bch, Bcl, P);
    ru2f_k<<<(2097152 + 255) / 256, 256, 0, stream>>>(P, G0T, Bc[ci], U, h);
  };

  for (int t = 0; t < 12; ++t) {
    cell(0, 2, inputs, 0, t, h0);
    cell(1, 64, h0, 2, 0, h1);
  }
  for (int k = 0; k < 12; ++k) {
    cell(2, 1, ybuf, 1, 0, h0);
    cell(3, 64, h0, 2, 0, h1);
    proj_out_k<<<(B_ * N_ + 255) / 256, 256, 0, stream>>>(h1, proj_w, proj_b, ybuf, out, k);
  }
}

// Round 8
// 9636.404 us; speedup vs baseline: 1.5496x; 1.1895x over previous
//
#include <hip/hip_runtime.h>

#define B_ 64
#define N_ 512

typedef __attribute__((ext_vector_type(8))) short bf8_t;    // 8 bf16 (4 VGPRs)
typedef __attribute__((ext_vector_type(16))) float f16_t;   // 32x32 MFMA acc

#define MFMA32(a, b, c) __builtin_amdgcn_mfma_f32_32x32x16_bf16(a, b, c, 0, 0, 0)

__device__ __forceinline__ ushort f2bf(float x) {
  union { float f; unsigned u; } v; v.f = x;
  unsigned r = v.u + 0x7FFFu + ((v.u >> 16) & 1u);   // RNE
  return (ushort)(r >> 16);
}
__device__ __forceinline__ float bf2f(ushort h) {
  union { unsigned u; float f; } v; v.u = ((unsigned)h) << 16;
  return v.f;
}

__device__ __forceinline__ void gld16(const ushort* g, ushort* l) {
  __builtin_amdgcn_global_load_lds(
      (const __attribute__((address_space(1))) unsigned int*)(uintptr_t)g,
      (__attribute__((address_space(3))) unsigned int*)(uintptr_t)l,
      16, 0, 0);
}

// XOR swizzle (BK=32: 4x 16B slots/row; (r>>1)&3 spread → 2-way = free)
__device__ __forceinline__ int swz32(int r) { return (r >> 1) & 3; }

template <int ROWS, int THREADS>
__device__ __forceinline__ void stage_tile2(const ushort* g, int lda, int k0,
                                            ushort* l, int tid) {
  constexpr int RT = (ROWS * 32) / (THREADS * 8);
#pragma unroll
  for (int q = 0; q < RT; ++q) {
    int e  = q * THREADS * 8 + tid * 8;
    int r  = e >> 5;
    int c8 = (e >> 3) & 3;
    int g8 = c8 ^ swz32(r);
    gld16(g + (size_t)r * lda + k0 + g8 * 8, l + e);
  }
}

// ---------------------------------------------------------------------------
// Split-bf16 GEMM core: C[m][n] = sum_k A[m][k]*B[n][k], both K-contiguous.
// 128x128 tile, BK=32, double-buffered 64KB LDS, 3-term 32x32x16 MFMA,
// 2x2 waves, wave tile 64x64 = 2x2 frags of 32x32.
// ---------------------------------------------------------------------------
__device__ __forceinline__ void core128(
    const ushort* Ah, const ushort* Al, int lda,
    const ushort* Bh, const ushort* Bl, int ldb,
    int K, ushort* lds, f16_t acc[2][2]) {
  constexpr int TILE = 128 * 32;
  constexpr int SSZ  = 4 * TILE;
  const int tid = threadIdx.x, lane = tid & 63, wave = tid >> 6;
  const int ar = lane & 31, hb = lane >> 5;
  const int wm = wave >> 1, wn = wave & 1;

  auto stage = [&](int buf, int k0) {
    ushort* lb = lds + buf * SSZ;
    stage_tile2<128, 256>(Ah, lda, k0, lb, tid);
    stage_tile2<128, 256>(Al, lda, k0, lb + TILE, tid);
    stage_tile2<128, 256>(Bh, ldb, k0, lb + 2 * TILE, tid);
    stage_tile2<128, 256>(Bl, ldb, k0, lb + 3 * TILE, tid);
  };

  const int nc = K >> 5;
  stage(0, 0);
  int buf = 0;
  for (int c = 0; c < nc; ++c) {
    __syncthreads();
    if (c + 1 < nc) stage(buf ^ 1, (c + 1) << 5);
    const ushort* lb = lds + buf * SSZ;
#pragma unroll
    for (int ks = 0; ks < 2; ++ks) {
      bf8_t ah[2], al[2], bh[2], bl[2];
#pragma unroll
      for (int i = 0; i < 2; ++i) {
        int r = wm * 64 + 32 * i + ar;
        int c8 = (ks * 2 + hb) ^ swz32(r);
        ah[i] = *(const bf8_t*)(lb + r * 32 + c8 * 8);
        al[i] = *(const bf8_t*)(lb + TILE + r * 32 + c8 * 8);
      }
#pragma unroll
      for (int j = 0; j < 2; ++j) {
        int r = wn * 64 + 32 * j + ar;
        int c8 = (ks * 2 + hb) ^ swz32(r);
        bh[j] = *(const bf8_t*)(lb + 2 * TILE + r * 32 + c8 * 8);
        bl[j] = *(const bf8_t*)(lb + 3 * TILE + r * 32 + c8 * 8);
      }
#pragma unroll
      for (int i = 0; i < 2; ++i)
#pragma unroll
        for (int j = 0; j < 2; ++j) {
          acc[i][j] = MFMA32(ah[i], bh[j], acc[i][j]);
          acc[i][j] = MFMA32(ah[i], bl[j], acc[i][j]);
          acc[i][j] = MFMA32(al[i], bh[j], acc[i][j]);
        }
    }
    buf ^= 1;
  }
}

// C/D row-within-frag for 32x32: (r&3) + 8*(r>>2) + 4*hb
__device__ __forceinline__ int crow32(int r, int hb) {
  return (r & 3) + 8 * (r >> 2) + 4 * hb;
}

// ---------------------------------------------------------------------------
// Prep
// ---------------------------------------------------------------------------
__global__ __launch_bounds__(256) void ssq_k(const float* __restrict__ S,
                                             float* __restrict__ SS) {
  int s = blockIdx.z;
  const float* Ss = S + s * N_ * N_;
  __shared__ float Ta[16][17], Tb[16][17];
  int n = blockIdx.y * 16 + threadIdx.y;
  int m = blockIdx.x * 16 + threadIdx.x;
  float acc = 0.f;
  for (int p0 = 0; p0 < N_; p0 += 16) {
    Ta[threadIdx.y][threadIdx.x] = Ss[n * N_ + p0 + threadIdx.x];
    Tb[threadIdx.y][threadIdx.x] = Ss[(p0 + threadIdx.y) * N_ + m];
    __syncthreads();
#pragma unroll
    for (int pp = 0; pp < 16; ++pp)
      acc = fmaf(Ta[threadIdx.y][pp], Tb[pp][threadIdx.x], acc);
    __syncthreads();
  }
  SS[((size_t)s * N_ + n) * N_ + m] = acc;
}

// Bcat[n][k], k = seg*512+m, segs [S0, S0^2, S1, S1^2], split hi/lo
__global__ __launch_bounds__(256) void bcat_k(const float* __restrict__ S,
                                              const float* __restrict__ SS,
                                              ushort* __restrict__ Bh,
                                              ushort* __restrict__ Bl) {
  int idx = blockIdx.x * 256 + threadIdx.x;
  if (idx >= 512 * 2048) return;
  int k = idx & 2047, n = idx >> 11;
  int seg = k >> 9, m = k & 511;
  float v;
  if (seg == 0)      v = S[(size_t)n * 512 + m];
  else if (seg == 1) v = SS[(size_t)n * 512 + m];
  else if (seg == 2) v = S[(size_t)(512 + n) * 512 + m];
  else               v = SS[(size_t)(512 + n) * 512 + m];
  ushort hh = f2bf(v);
  Bh[idx] = hh; Bl[idx] = f2bf(v - bf2f(hh));
}

// Wt[i = t*Dout + d][c] (128-wide rows) from W[(t*C+c)*Dout + d]; zeros outside
__global__ __launch_bounds__(256) void wprep2_k(const float* __restrict__ W,
                                                ushort* __restrict__ Wh,
                                                ushort* __restrict__ Wl,
                                                int C, int Dout, int Mt) {
  int idx = blockIdx.x * 256 + threadIdx.x;
  if (idx >= Mt * 128) return;
  int c = idx & 127, i = idx >> 7;
  int t = i / Dout, d = i % Dout;
  float v = (c < C && t < 5) ? W[(size_t)(t * C + c) * Dout + d] : 0.f;
  ushort hh = f2bf(v);
  Wh[idx] = hh; Wl[idx] = f2bf(v - bf2f(hh));
}

// ---------------------------------------------------------------------------
// Pack zT[(b,n)][c] = [x | h | 0-pad], split hi/lo. hT is [(b,n)][d].
// xmode 0: inputs gather (t); xmode 1: flat [jg]; xmode 2: hT-row layout
// ---------------------------------------------------------------------------
__global__ __launch_bounds__(256) void packzT_k(const float* __restrict__ xsrc,
                                                int xmode, int t, int Cx, int C,
                                                const float* __restrict__ hT,
                                                ushort* __restrict__ Zh,
                                                ushort* __restrict__ Zl) {
  int jg = blockIdx.x * 256 + threadIdx.x;   // b*512 + n
  int b = jg >> 9, n = jg & 511;
  for (int c0 = 0; c0 < 128; c0 += 8) {
    bf8_t vh, vl;
#pragma unroll
    for (int q = 0; q < 8; ++q) {
      int c = c0 + q;
      float v;
      if (c < Cx) {
        if (xmode == 0)      v = xsrc[((size_t)(b * Cx + c) * 512 + n) * 12 + t];
        else if (xmode == 1) v = xsrc[jg];
        else                 v = xsrc[(size_t)jg * 64 + c];
      } else if (c < C) {
        v = hT[(size_t)jg * 64 + (c - Cx)];
      } else {
        v = 0.f;
      }
      ushort hh = f2bf(v);
      vh[q] = (short)hh;
      vl[q] = (short)f2bf(v - bf2f(hh));
    }
    *(bf8_t*)(Zh + (size_t)jg * 128 + c0) = vh;
    *(bf8_t*)(Zl + (size_t)jg * 128 + c0) = vl;
  }
}

// ---------------------------------------------------------------------------
// Step 1: G = Wt * zT^T. A = Wt (Mt x 128), B = zT (32768 x 128), K=K1.
// t=0 rows -> f32 G0T[jg][d]; t>=1 -> Gh/Gl[(b*DR+d)*2048+(t-1)*512+m]
// MODE 0: DR=128 (gate); MODE 1: DR=64 (cand)
// ---------------------------------------------------------------------------
template <int MODE>
__global__ __launch_bounds__(256, 2) void g1_k(const ushort* __restrict__ Wh,
                                               const ushort* __restrict__ Wl,
                                               const ushort* __restrict__ Zh,
                                               const ushort* __restrict__ Zl,
                                               ushort* __restrict__ Gh,
                                               ushort* __restrict__ Gl,
                                               float* __restrict__ G0T,
                                               int K, int Mlimit) {
  __shared__ __attribute__((aligned(16))) ushort lds[2 * 4 * 128 * 32];
  constexpr int DR = (MODE == 0) ? 128 : 64;
  int tid = threadIdx.x, lane = tid & 63, wave = tid >> 6;
  int wm = wave >> 1, wn = wave & 1, ar = lane & 31, hb = lane >> 5;
  int nt = blockIdx.x, mt = blockIdx.y;
  f16_t acc[2][2] = {};
  core128(Wh + (size_t)mt * 128 * 128, Wl + (size_t)mt * 128 * 128, 128,
          Zh + (size_t)nt * 128 * 128, Zl + (size_t)nt * 128 * 128, 128,
          K, lds, acc);
#pragma unroll
  for (int i = 0; i < 2; ++i)
#pragma unroll
    for (int j = 0; j < 2; ++j) {
      int jg = nt * 128 + wn * 64 + 32 * j + ar;   // b*512 + m
      int b = jg >> 9, m = jg & 511;
#pragma unroll
      for (int r = 0; r < 16; ++r) {
        int ii = mt * 128 + wm * 64 + 32 * i + crow32(r, hb);
        if (ii >= Mlimit) continue;
        float v = acc[i][j][r];
        int t = ii / DR, d = ii % DR;
        if (t == 0) {
          G0T[(size_t)jg * DR + d] = v;
        } else {
          size_t addr = ((size_t)(b * DR + d)) * 2048 + (size_t)(t - 1) * 512 + m;
          ushort hh = f2bf(v);
          Gh[addr] = hh; Gl[addr] = f2bf(v - bf2f(hh));
        }
      }
    }
}

// ---------------------------------------------------------------------------
// Gate diffusion GEMM, split-K (kz=2 x 1024): C[node][R] partials -> P
// grid (nt=64 over R, mt=4 over node, kz=2) = 512 blocks.
// ---------------------------------------------------------------------------
__global__ __launch_bounds__(256, 2) void ru1g_k(const ushort* __restrict__ Gh,
                                                 const ushort* __restrict__ Gl,
                                                 const ushort* __restrict__ Bch,
                                                 const ushort* __restrict__ Bcl,
                                                 float* __restrict__ P) {
  __shared__ __attribute__((aligned(16))) ushort lds[2 * 4 * 128 * 32];
  int tid = threadIdx.x, lane = tid & 63, wave = tid >> 6;
  int wm = wave >> 1, wn = wave & 1, ar = lane & 31, hb = lane >> 5;
  int nt = blockIdx.x, mt = blockIdx.y, kz = blockIdx.z;
  f16_t acc[2][2] = {};
  core128(Bch + (size_t)mt * 128 * 2048 + kz * 1024,
          Bcl + (size_t)mt * 128 * 2048 + kz * 1024, 2048,
          Gh + (size_t)nt * 128 * 2048 + kz * 1024,
          Gl + (size_t)nt * 128 * 2048 + kz * 1024, 2048,
          1024, lds, acc);
  float* Pz = P + (size_t)kz * 4194304;
#pragma unroll
  for (int i = 0; i < 2; ++i)
#pragma unroll
    for (int j = 0; j < 2; ++j) {
      int R = nt * 128 + wn * 64 + 32 * j + ar;
      int b = R >> 7, d = R & 127;
#pragma unroll
      for (int r = 0; r < 16; ++r) {
        int node = mt * 128 + wm * 64 + 32 * i + crow32(r, hb);
        Pz[((size_t)b * 512 + node) * 128 + d] = acc[i][j][r];
      }
    }
}

// finish gate: sigmoid(P0+P1+G0T+bg); d<64 -> r*h into zT; d>=64 -> u into U
__global__ __launch_bounds__(256) void ru1f_k(const float* __restrict__ P,
                                              const float* __restrict__ G0T,
                                              const float* __restrict__ bg,
                                              const float* __restrict__ hT,
                                              float* __restrict__ U,
                                              ushort* __restrict__ Zh,
                                              ushort* __restrict__ Zl, int Cx) {
  int idx = blockIdx.x * 256 + threadIdx.x;
  if (idx >= 4194304) return;
  int row = idx >> 7, d = idx & 127;
  float s = P[idx] + P[idx + 4194304] + G0T[idx] + bg[d];
  s = 1.f / (1.f + expf(-s));
  if (d < 64) {
    float rh = s * hT[(size_t)row * 64 + d];
    ushort hh = f2bf(rh);
    Zh[(size_t)row * 128 + Cx + d] = hh;
    Zl[(size_t)row * 128 + Cx + d] = f2bf(rh - bf2f(hh));
  } else {
    U[(size_t)row * 64 + (d - 64)] = s;
  }
}

// ---------------------------------------------------------------------------
// Cand diffusion GEMM, split-K (kz=4 x 512): grid (nt=32, mt=4, kz=4) = 512.
// ---------------------------------------------------------------------------
__global__ __launch_bounds__(256, 2) void ru2g_k(const ushort* __restrict__ Gh,
                                                 const ushort* __restrict__ Gl,
                                                 const ushort* __restrict__ Bch,
                                                 const ushort* __restrict__ Bcl,
                                                 float* __restrict__ P) {
  __shared__ __attribute__((aligned(16))) ushort lds[2 * 4 * 128 * 32];
  int tid = threadIdx.x, lane = tid & 63, wave = tid >> 6;
  int wm = wave >> 1, wn = wave & 1, ar = lane & 31, hb = lane >> 5;
  int nt = blockIdx.x, mt = blockIdx.y, kz = blockIdx.z;
  f16_t acc[2][2] = {};
  core128(Bch + (size_t)mt * 128 * 2048 + kz * 512,
          Bcl + (size_t)mt * 128 * 2048 + kz * 512, 2048,
          Gh + (size_t)nt * 128 * 2048 + kz * 512,
          Gl + (size_t)nt * 128 * 2048 + kz * 512, 2048,
          512, lds, acc);
  float* Pz = P + (size_t)kz * 2097152;
#pragma unroll
  for (int i = 0; i < 2; ++i)
#pragma unroll
    for (int j = 0; j < 2; ++j) {
      int R = nt * 128 + wn * 64 + 32 * j + ar;
      int b = R >> 6, d = R & 63;
#pragma unroll
      for (int r = 0; r < 16; ++r) {
        int node = mt * 128 + wm * 64 + 32 * i + crow32(r, hb);
        Pz[((size_t)b * 512 + node) * 64 + d] = acc[i][j][r];
      }
    }
}

// finish cand: c~ = tanh(sum P + G0c + bc); h = u*h + (1-u)*c~
__global__ __launch_bounds__(256) void ru2f_k(const float* __restrict__ P,
                                              const float* __restrict__ G0c,
                                              const float* __restrict__ bc,
                                              const float* __restrict__ U,
                                              float* __restrict__ hT) {
  int idx = blockIdx.x * 256 + threadIdx.x;
  if (idx >= 2097152) return;
  float ct = tanhf(P[idx] + P[idx + 2097152] + P[idx + 2 * 2097152] +
                   P[idx + 3 * 2097152] + G0c[idx] + bc[idx & 63]);
  float u = U[idx];
  hT[idx] = u * hT[idx] + (1.f - u) * ct;
}

__global__ __launch_bounds__(256) void proj_out_k(const float* __restrict__ h1T,
                                                  const float* __restrict__ pw,
                                                  const float* __restrict__ pb,
                                                  float* __restrict__ ybuf,
                                                  float* __restrict__ out, int k) {
  int idx = blockIdx.x * blockDim.x + threadIdx.x;
  if (idx >= B_ * N_) return;
  float s = pb[0];
  const float* hrow = h1T + (size_t)idx * 64;
#pragma unroll
  for (int j = 0; j < 64; ++j)
    s = fmaf(pw[j], hrow[j], s);
  ybuf[idx] = s;
  out[(size_t)idx * 12 + k] = s;
}

extern "C" void kernel_launch(void* const* d_in, const int* in_sizes, int n_in,
                              void* d_out, int out_size, void* d_ws, size_t ws_size,
                              hipStream_t stream) {
  const float* inputs   = (const float*)d_in[0];
  const float* supports = (const float*)d_in[1];
  const float* Wg[4] = { (const float*)d_in[2],  (const float*)d_in[6],
                         (const float*)d_in[10], (const float*)d_in[14] };
  const float* Bg[4] = { (const float*)d_in[3],  (const float*)d_in[7],
                         (const float*)d_in[11], (const float*)d_in[15] };
  const float* Wc[4] = { (const float*)d_in[4],  (const float*)d_in[8],
                         (const float*)d_in[12], (const float*)d_in[16] };
  const float* Bc[4] = { (const float*)d_in[5],  (const float*)d_in[9],
                         (const float*)d_in[13], (const float*)d_in[17] };
  const float* proj_w = (const float*)d_in[18];
  const float* proj_b = (const float*)d_in[19];
  float* out = (float*)d_out;

  char* p = (char*)d_ws;
  auto carve = [&](size_t bytes) { void* q = p; p += (bytes + 255) & ~(size_t)255; return q; };
  ushort* Bch = (ushort*)carve((size_t)512 * 2048 * 2);
  ushort* Bcl = (ushort*)carve((size_t)512 * 2048 * 2);
  ushort* zTh = (ushort*)carve((size_t)32768 * 128 * 2);
  ushort* zTl = (ushort*)carve((size_t)32768 * 128 * 2);
  ushort* Gh  = (ushort*)carve((size_t)8192 * 2048 * 2);
  ushort* Gl  = (ushort*)carve((size_t)8192 * 2048 * 2);
  float*  G0T = (float*)carve((size_t)32768 * 128 * 4);
  float*  P   = (float*)carve((size_t)2 * 4194304 * 4);   // 32MB: ru1 2x / ru2 4x partials
  float*  U   = (float*)carve((size_t)2097152 * 4);
  float*  h0  = (float*)carve((size_t)2097152 * 4);
  float*  h1  = (float*)carve((size_t)2097152 * 4);
  float*  ybuf = (float*)carve((size_t)B_ * N_ * 4);
  ushort* Wgh[4]; ushort* Wgl[4]; ushort* Wch[4]; ushort* Wcl[4];
  for (int c = 0; c < 4; ++c) {
    Wgh[c] = (ushort*)carve((size_t)640 * 128 * 2);
    Wgl[c] = (ushort*)carve((size_t)640 * 128 * 2);
    Wch[c] = (ushort*)carve((size_t)384 * 128 * 2);
    Wcl[c] = (ushort*)carve((size_t)384 * 128 * 2);
  }
  float* SSbuf = (float*)U;      // SS only needed during prep

  hipMemsetAsync(h0, 0, (size_t)2097152 * 4, stream);
  hipMemsetAsync(h1, 0, (size_t)2097152 * 4, stream);
  hipMemsetAsync(ybuf, 0, (size_t)B_ * N_ * 4, stream);

  ssq_k<<<dim3(32, 32, 2), dim3(16, 16), 0, stream>>>(supports, SSbuf);
  bcat_k<<<(512 * 2048 + 255) / 256, 256, 0, stream>>>(supports, SSbuf, Bch, Bcl);
  const int Cs[4] = { 66, 128, 65, 128 };
  for (int c = 0; c < 4; ++c) {
    wprep2_k<<<(640 * 128 + 255) / 256, 256, 0, stream>>>(Wg[c], Wgh[c], Wgl[c], Cs[c], 128, 640);
    wprep2_k<<<(384 * 128 + 255) / 256, 256, 0, stream>>>(Wc[c], Wch[c], Wcl[c], Cs[c], 64, 384);
  }

  auto cell = [&](int ci, int Cx, const float* x, int xmode, int t, float* h) {
    int C = Cx + 64;
    int K1 = (C + 31) & ~31;   // 96 or 128
    packzT_k<<<128, 256, 0, stream>>>(x, xmode, t, Cx, C, h, zTh, zTl);
    g1_k<0><<<dim3(256, 5), 256, 0, stream>>>(Wgh[ci], Wgl[ci], zTh, zTl, Gh, Gl, G0T, K1, 640);
    ru1g_k<<<dim3(64, 4, 2), 256, 0, stream>>>(Gh, Gl, Bch, Bcl, P);
    ru1f_k<<<16384, 256, 0, stream>>>(P, G0T, Bg[ci], h, U, zTh, zTl, Cx);
    g1_k<1><<<dim3(256, 3), 256, 0, stream>>>(Wch[ci], Wcl[ci], zTh, zTl, Gh, Gl, G0T, K1, 320);
    ru2g_k<<<dim3(32, 4, 4), 256, 0, stream>>>(Gh, Gl, Bch, Bcl, P);
    ru2f_k<<<8192, 256, 0, stream>>>(P, G0T, Bc[ci], U, h);
  };

  for (int t = 0; t < 12; ++t) {
    cell(0, 2, inputs, 0, t, h0);
    cell(1, 64, h0, 2, 0, h1);
  }
  for (int k = 0; k < 12; ++k) {
    cell(2, 1, ybuf, 1, 0, h0);
    cell(3, 64, h0, 2, 0, h1);
    proj_out_k<<<(B_ * N_ + 255) / 256, 256, 0, stream>>>(h1, proj_w, proj_b, ybuf, out, k);
  }
}

// Round 9
// 9496.707 us; speedup vs baseline: 1.5724x; 1.0147x over previous
//
#include <hip/hip_runtime.h>

#define B_ 64
#define N_ 512

typedef __attribute__((ext_vector_type(8))) short bf8_t;    // 8 bf16 (4 VGPRs)
typedef __attribute__((ext_vector_type(16))) float f16_t;   // 32x32 MFMA acc
typedef __attribute__((ext_vector_type(4))) float f4v_t;

#define MFMA32(a, b, c) __builtin_amdgcn_mfma_f32_32x32x16_bf16(a, b, c, 0, 0, 0)

__device__ __forceinline__ ushort f2bf(float x) {
  union { float f; unsigned u; } v; v.f = x;
  unsigned r = v.u + 0x7FFFu + ((v.u >> 16) & 1u);   // RNE
  return (ushort)(r >> 16);
}
__device__ __forceinline__ float bf2f(ushort h) {
  union { unsigned u; float f; } v; v.u = ((unsigned)h) << 16;
  return v.f;
}

__device__ __forceinline__ void gld16(const ushort* g, ushort* l) {
  __builtin_amdgcn_global_load_lds(
      (const __attribute__((address_space(1))) unsigned int*)(uintptr_t)g,
      (__attribute__((address_space(3))) unsigned int*)(uintptr_t)l,
      16, 0, 0);
}

// XCD-aware bijective swizzle: consecutive LOGICAL ids land on the same XCD
// (assumes dispatcher round-robins linear block id over 8 XCDs; worst case a
// wrong assumption is a neutral permutation). nwg must be divisible by 8.
__device__ __forceinline__ int xcd_logical(int nwg) {
  int lin = blockIdx.x + gridDim.x * (blockIdx.y + gridDim.y * blockIdx.z);
  return (lin & 7) * (nwg >> 3) + (lin >> 3);
}

// XOR swizzle (BK=32: 4x 16B slots/row; (r>>1)&3 spread → 2-way = free)
__device__ __forceinline__ int swz32(int r) { return (r >> 1) & 3; }

template <int ROWS, int THREADS>
__device__ __forceinline__ void stage_tile2(const ushort* g, int lda, int k0,
                                            ushort* l, int tid) {
  constexpr int RT = (ROWS * 32) / (THREADS * 8);
#pragma unroll
  for (int q = 0; q < RT; ++q) {
    int e  = q * THREADS * 8 + tid * 8;
    int r  = e >> 5;
    int c8 = (e >> 3) & 3;
    int g8 = c8 ^ swz32(r);
    gld16(g + (size_t)r * lda + k0 + g8 * 8, l + e);
  }
}

// ---------------------------------------------------------------------------
// Split-bf16 GEMM core: C[m][n] = sum_k A[m][k]*B[n][k], both K-contiguous.
// 128x128 tile, BK=32, double-buffered 64KB LDS, 3-term 32x32x16 MFMA,
// 2x2 waves, wave tile 64x64 = 2x2 frags of 32x32.
// ---------------------------------------------------------------------------
__device__ __forceinline__ void core128(
    const ushort* Ah, const ushort* Al, int lda,
    const ushort* Bh, const ushort* Bl, int ldb,
    int K, ushort* lds, f16_t acc[2][2]) {
  constexpr int TILE = 128 * 32;
  constexpr int SSZ  = 4 * TILE;
  const int tid = threadIdx.x, lane = tid & 63, wave = tid >> 6;
  const int ar = lane & 31, hb = lane >> 5;
  const int wm = wave >> 1, wn = wave & 1;

  auto stage = [&](int buf, int k0) {
    ushort* lb = lds + buf * SSZ;
    stage_tile2<128, 256>(Ah, lda, k0, lb, tid);
    stage_tile2<128, 256>(Al, lda, k0, lb + TILE, tid);
    stage_tile2<128, 256>(Bh, ldb, k0, lb + 2 * TILE, tid);
    stage_tile2<128, 256>(Bl, ldb, k0, lb + 3 * TILE, tid);
  };

  const int nc = K >> 5;
  stage(0, 0);
  int buf = 0;
  for (int c = 0; c < nc; ++c) {
    __syncthreads();
    if (c + 1 < nc) stage(buf ^ 1, (c + 1) << 5);
    const ushort* lb = lds + buf * SSZ;
#pragma unroll
    for (int ks = 0; ks < 2; ++ks) {
      bf8_t ah[2], al[2], bh[2], bl[2];
#pragma unroll
      for (int i = 0; i < 2; ++i) {
        int r = wm * 64 + 32 * i + ar;
        int c8 = (ks * 2 + hb) ^ swz32(r);
        ah[i] = *(const bf8_t*)(lb + r * 32 + c8 * 8);
        al[i] = *(const bf8_t*)(lb + TILE + r * 32 + c8 * 8);
      }
#pragma unroll
      for (int j = 0; j < 2; ++j) {
        int r = wn * 64 + 32 * j + ar;
        int c8 = (ks * 2 + hb) ^ swz32(r);
        bh[j] = *(const bf8_t*)(lb + 2 * TILE + r * 32 + c8 * 8);
        bl[j] = *(const bf8_t*)(lb + 3 * TILE + r * 32 + c8 * 8);
      }
#pragma unroll
      for (int i = 0; i < 2; ++i)
#pragma unroll
        for (int j = 0; j < 2; ++j) {
          acc[i][j] = MFMA32(ah[i], bh[j], acc[i][j]);
          acc[i][j] = MFMA32(ah[i], bl[j], acc[i][j]);
          acc[i][j] = MFMA32(al[i], bh[j], acc[i][j]);
        }
    }
    buf ^= 1;
  }
}

// C/D row-within-frag for 32x32: (r&3) + 8*(r>>2) + 4*hb
__device__ __forceinline__ int crow32(int r, int hb) {
  return (r & 3) + 8 * (r >> 2) + 4 * hb;
}

// ---------------------------------------------------------------------------
// Prep
// ---------------------------------------------------------------------------
__global__ __launch_bounds__(256) void ssq_k(const float* __restrict__ S,
                                             float* __restrict__ SS) {
  int s = blockIdx.z;
  const float* Ss = S + s * N_ * N_;
  __shared__ float Ta[16][17], Tb[16][17];
  int n = blockIdx.y * 16 + threadIdx.y;
  int m = blockIdx.x * 16 + threadIdx.x;
  float acc = 0.f;
  for (int p0 = 0; p0 < N_; p0 += 16) {
    Ta[threadIdx.y][threadIdx.x] = Ss[n * N_ + p0 + threadIdx.x];
    Tb[threadIdx.y][threadIdx.x] = Ss[(p0 + threadIdx.y) * N_ + m];
    __syncthreads();
#pragma unroll
    for (int pp = 0; pp < 16; ++pp)
      acc = fmaf(Ta[threadIdx.y][pp], Tb[pp][threadIdx.x], acc);
    __syncthreads();
  }
  SS[((size_t)s * N_ + n) * N_ + m] = acc;
}

// Bcat[n][k], k = seg*512+m, segs [S0, S0^2, S1, S1^2], split hi/lo
__global__ __launch_bounds__(256) void bcat_k(const float* __restrict__ S,
                                              const float* __restrict__ SS,
                                              ushort* __restrict__ Bh,
                                              ushort* __restrict__ Bl) {
  int idx = blockIdx.x * 256 + threadIdx.x;
  if (idx >= 512 * 2048) return;
  int k = idx & 2047, n = idx >> 11;
  int seg = k >> 9, m = k & 511;
  float v;
  if (seg == 0)      v = S[(size_t)n * 512 + m];
  else if (seg == 1) v = SS[(size_t)n * 512 + m];
  else if (seg == 2) v = S[(size_t)(512 + n) * 512 + m];
  else               v = SS[(size_t)(512 + n) * 512 + m];
  ushort hh = f2bf(v);
  Bh[idx] = hh; Bl[idx] = f2bf(v - bf2f(hh));
}

// Wt[i = t*Dout + d][c] (128-wide rows) from W[(t*C+c)*Dout + d]; zeros outside
__global__ __launch_bounds__(256) void wprep2_k(const float* __restrict__ W,
                                                ushort* __restrict__ Wh,
                                                ushort* __restrict__ Wl,
                                                int C, int Dout, int Mt) {
  int idx = blockIdx.x * 256 + threadIdx.x;
  if (idx >= Mt * 128) return;
  int c = idx & 127, i = idx >> 7;
  int t = i / Dout, d = i % Dout;
  float v = (c < C && t < 5) ? W[(size_t)(t * C + c) * Dout + d] : 0.f;
  ushort hh = f2bf(v);
  Wh[idx] = hh; Wl[idx] = f2bf(v - bf2f(hh));
}

// ---------------------------------------------------------------------------
// Pack zT[(b,n)][c] = [x | h | 0-pad], split hi/lo. hT is [(b,n)][d].
// xmode 0: inputs gather (t); xmode 1: flat [jg]; xmode 2: hT-row layout
// ---------------------------------------------------------------------------
__global__ __launch_bounds__(256) void packzT_k(const float* __restrict__ xsrc,
                                                int xmode, int t, int Cx, int C,
                                                const float* __restrict__ hT,
                                                ushort* __restrict__ Zh,
                                                ushort* __restrict__ Zl) {
  int jg = blockIdx.x * 256 + threadIdx.x;   // b*512 + n
  int b = jg >> 9, n = jg & 511;
  for (int c0 = 0; c0 < 128; c0 += 8) {
    bf8_t vh, vl;
#pragma unroll
    for (int q = 0; q < 8; ++q) {
      int c = c0 + q;
      float v;
      if (c < Cx) {
        if (xmode == 0)      v = xsrc[((size_t)(b * Cx + c) * 512 + n) * 12 + t];
        else if (xmode == 1) v = xsrc[jg];
        else                 v = xsrc[(size_t)jg * 64 + c];
      } else if (c < C) {
        v = hT[(size_t)jg * 64 + (c - Cx)];
      } else {
        v = 0.f;
      }
      ushort hh = f2bf(v);
      vh[q] = (short)hh;
      vl[q] = (short)f2bf(v - bf2f(hh));
    }
    *(bf8_t*)(Zh + (size_t)jg * 128 + c0) = vh;
    *(bf8_t*)(Zl + (size_t)jg * 128 + c0) = vl;
  }
}

// ---------------------------------------------------------------------------
// Step 1: G = Wt * zT^T. A = Wt (Mt x 128), B = zT (32768 x 128), K=K1.
// t=0 rows -> f32 G0T[jg][d]; t>=1 -> Gh/Gl[(b*DR+d)*2048+(t-1)*512+m]
// MODE 0: DR=128 (gate, NMT=5); MODE 1: DR=64 (cand, NMT=3)
// Logical order mt-fastest + XCD swizzle: the NMT sharers of a zT tile run
// concurrently on one XCD.
// ---------------------------------------------------------------------------
template <int MODE>
__global__ __launch_bounds__(256, 2) void g1_k(const ushort* __restrict__ Wh,
                                               const ushort* __restrict__ Wl,
                                               const ushort* __restrict__ Zh,
                                               const ushort* __restrict__ Zl,
                                               ushort* __restrict__ Gh,
                                               ushort* __restrict__ Gl,
                                               float* __restrict__ G0T,
                                               int K, int Mlimit) {
  __shared__ __attribute__((aligned(16))) ushort lds[2 * 4 * 128 * 32];
  constexpr int DR = (MODE == 0) ? 128 : 64;
  constexpr int NMT = (MODE == 0) ? 5 : 3;
  int tid = threadIdx.x, lane = tid & 63, wave = tid >> 6;
  int wm = wave >> 1, wn = wave & 1, ar = lane & 31, hb = lane >> 5;
  int L = xcd_logical(256 * NMT);
  int mt = L % NMT, nt = L / NMT;
  f16_t acc[2][2] = {};
  core128(Wh + (size_t)mt * 128 * 128, Wl + (size_t)mt * 128 * 128, 128,
          Zh + (size_t)nt * 128 * 128, Zl + (size_t)nt * 128 * 128, 128,
          K, lds, acc);
#pragma unroll
  for (int i = 0; i < 2; ++i)
#pragma unroll
    for (int j = 0; j < 2; ++j) {
      int jg = nt * 128 + wn * 64 + 32 * j + ar;   // b*512 + m
      int b = jg >> 9, m = jg & 511;
#pragma unroll
      for (int r = 0; r < 16; ++r) {
        int ii = mt * 128 + wm * 64 + 32 * i + crow32(r, hb);
        if (ii >= Mlimit) continue;
        float v = acc[i][j][r];
        int t = ii / DR, d = ii % DR;
        if (t == 0) {
          G0T[(size_t)jg * DR + d] = v;
        } else {
          size_t addr = ((size_t)(b * DR + d)) * 2048 + (size_t)(t - 1) * 512 + m;
          ushort hh = f2bf(v);
          Gh[addr] = hh; Gl[addr] = f2bf(v - bf2f(hh));
        }
      }
    }
}

// ---------------------------------------------------------------------------
// Gate diffusion GEMM, split-K (kz=2 x 1024): C[node][R] partials -> P
// logical 512 = (mt fastest 4, nt 64, kz 2); XCD swizzle: 4 mt-sharers of a
// G tile co-resident on one XCD (G tile fetched once into that L2).
// ---------------------------------------------------------------------------
__global__ __launch_bounds__(256, 2) void ru1g_k(const ushort* __restrict__ Gh,
                                                 const ushort* __restrict__ Gl,
                                                 const ushort* __restrict__ Bch,
                                                 const ushort* __restrict__ Bcl,
                                                 float* __restrict__ P) {
  __shared__ __attribute__((aligned(16))) ushort lds[2 * 4 * 128 * 32];
  int tid = threadIdx.x, lane = tid & 63, wave = tid >> 6;
  int wm = wave >> 1, wn = wave & 1, ar = lane & 31, hb = lane >> 5;
  int L = xcd_logical(512);
  int mt = L & 3, nt = (L >> 2) & 63, kz = L >> 8;
  f16_t acc[2][2] = {};
  core128(Bch + (size_t)mt * 128 * 2048 + kz * 1024,
          Bcl + (size_t)mt * 128 * 2048 + kz * 1024, 2048,
          Gh + (size_t)nt * 128 * 2048 + kz * 1024,
          Gl + (size_t)nt * 128 * 2048 + kz * 1024, 2048,
          1024, lds, acc);
  float* Pz = P + (size_t)kz * 4194304;
#pragma unroll
  for (int i = 0; i < 2; ++i)
#pragma unroll
    for (int j = 0; j < 2; ++j) {
      int R = nt * 128 + wn * 64 + 32 * j + ar;
      int b = R >> 7, d = R & 127;
#pragma unroll
      for (int r = 0; r < 16; ++r) {
        int node = mt * 128 + wm * 64 + 32 * i + crow32(r, hb);
        Pz[((size_t)b * 512 + node) * 128 + d] = acc[i][j][r];
      }
    }
}

// finish gate: sigmoid(P0+P1+G0T+bg); d<64 -> r*h into zT; d>=64 -> u into U
__global__ __launch_bounds__(256) void ru1f_k(const float* __restrict__ P,
                                              const float* __restrict__ G0T,
                                              const float* __restrict__ bg,
                                              const float* __restrict__ hT,
                                              float* __restrict__ U,
                                              ushort* __restrict__ Zh,
                                              ushort* __restrict__ Zl, int Cx) {
  int i4 = blockIdx.x * 256 + threadIdx.x;
  if (i4 >= 1048576) return;
  int base = i4 * 4;
  int row = base >> 7, d = base & 127;
  f4v_t p0 = *(const f4v_t*)(P + base);
  f4v_t p1 = *(const f4v_t*)(P + 4194304 + base);
  f4v_t g0 = *(const f4v_t*)(G0T + base);
  if (d < 64) {
    f4v_t hv = *(const f4v_t*)(hT + (size_t)row * 64 + d);
#pragma unroll
    for (int e = 0; e < 4; ++e) {
      float s = 1.f / (1.f + expf(-(p0[e] + p1[e] + g0[e] + bg[d + e])));
      float rh = s * hv[e];
      ushort hh = f2bf(rh);
      Zh[(size_t)row * 128 + Cx + d + e] = hh;
      Zl[(size_t)row * 128 + Cx + d + e] = f2bf(rh - bf2f(hh));
    }
  } else {
    f4v_t uo;
#pragma unroll
    for (int e = 0; e < 4; ++e)
      uo[e] = 1.f / (1.f + expf(-(p0[e] + p1[e] + g0[e] + bg[d + e])));
    *(f4v_t*)(U + (size_t)row * 64 + (d - 64)) = uo;
  }
}

// ---------------------------------------------------------------------------
// Cand diffusion GEMM, split-K (kz=4 x 512): logical (mt 4, nt 32, kz 4).
// ---------------------------------------------------------------------------
__global__ __launch_bounds__(256, 2) void ru2g_k(const ushort* __restrict__ Gh,
                                                 const ushort* __restrict__ Gl,
                                                 const ushort* __restrict__ Bch,
                                                 const ushort* __restrict__ Bcl,
                                                 float* __restrict__ P) {
  __shared__ __attribute__((aligned(16))) ushort lds[2 * 4 * 128 * 32];
  int tid = threadIdx.x, lane = tid & 63, wave = tid >> 6;
  int wm = wave >> 1, wn = wave & 1, ar = lane & 31, hb = lane >> 5;
  int L = xcd_logical(512);
  int mt = L & 3, nt = (L >> 2) & 31, kz = L >> 7;
  f16_t acc[2][2] = {};
  core128(Bch + (size_t)mt * 128 * 2048 + kz * 512,
          Bcl + (size_t)mt * 128 * 2048 + kz * 512, 2048,
          Gh + (size_t)nt * 128 * 2048 + kz * 512,
          Gl + (size_t)nt * 128 * 2048 + kz * 512, 2048,
          512, lds, acc);
  float* Pz = P + (size_t)kz * 2097152;
#pragma unroll
  for (int i = 0; i < 2; ++i)
#pragma unroll
    for (int j = 0; j < 2; ++j) {
      int R = nt * 128 + wn * 64 + 32 * j + ar;
      int b = R >> 6, d = R & 63;
#pragma unroll
      for (int r = 0; r < 16; ++r) {
        int node = mt * 128 + wm * 64 + 32 * i + crow32(r, hb);
        Pz[((size_t)b * 512 + node) * 64 + d] = acc[i][j][r];
      }
    }
}

// finish cand: c~ = tanh(sum P + G0c + bc); h = u*h + (1-u)*c~
__global__ __launch_bounds__(256) void ru2f_k(const float* __restrict__ P,
                                              const float* __restrict__ G0c,
                                              const float* __restrict__ bc,
                                              const float* __restrict__ U,
                                              float* __restrict__ hT) {
  int i4 = blockIdx.x * 256 + threadIdx.x;
  if (i4 >= 524288) return;
  int base = i4 * 4;
  int d = base & 63;
  f4v_t p0 = *(const f4v_t*)(P + base);
  f4v_t p1 = *(const f4v_t*)(P + 2097152 + base);
  f4v_t p2 = *(const f4v_t*)(P + 2 * 2097152 + base);
  f4v_t p3 = *(const f4v_t*)(P + 3 * 2097152 + base);
  f4v_t g0 = *(const f4v_t*)(G0c + base);
  f4v_t uv = *(const f4v_t*)(U + base);
  f4v_t hv = *(const f4v_t*)(hT + base);
#pragma unroll
  for (int e = 0; e < 4; ++e) {
    float ct = tanhf(p0[e] + p1[e] + p2[e] + p3[e] + g0[e] + bc[d + e]);
    hv[e] = uv[e] * hv[e] + (1.f - uv[e]) * ct;
  }
  *(f4v_t*)(hT + base) = hv;
}

__global__ __launch_bounds__(256) void proj_out_k(const float* __restrict__ h1T,
                                                  const float* __restrict__ pw,
                                                  const float* __restrict__ pb,
                                                  float* __restrict__ ybuf,
                                                  float* __restrict__ out, int k) {
  int idx = blockIdx.x * blockDim.x + threadIdx.x;
  if (idx >= B_ * N_) return;
  float s = pb[0];
  const float* hrow = h1T + (size_t)idx * 64;
#pragma unroll
  for (int j = 0; j < 64; ++j)
    s = fmaf(pw[j], hrow[j], s);
  ybuf[idx] = s;
  out[(size_t)idx * 12 + k] = s;
}

extern "C" void kernel_launch(void* const* d_in, const int* in_sizes, int n_in,
                              void* d_out, int out_size, void* d_ws, size_t ws_size,
                              hipStream_t stream) {
  const float* inputs   = (const float*)d_in[0];
  const float* supports = (const float*)d_in[1];
  const float* Wg[4] = { (const float*)d_in[2],  (const float*)d_in[6],
                         (const float*)d_in[10], (const float*)d_in[14] };
  const float* Bg[4] = { (const float*)d_in[3],  (const float*)d_in[7],
                         (const float*)d_in[11], (const float*)d_in[15] };
  const float* Wc[4] = { (const float*)d_in[4],  (const float*)d_in[8],
                         (const float*)d_in[12], (const float*)d_in[16] };
  const float* Bc[4] = { (const float*)d_in[5],  (const float*)d_in[9],
                         (const float*)d_in[13], (const float*)d_in[17] };
  const float* proj_w = (const float*)d_in[18];
  const float* proj_b = (const float*)d_in[19];
  float* out = (float*)d_out;

  char* p = (char*)d_ws;
  auto carve = [&](size_t bytes) { void* q = p; p += (bytes + 255) & ~(size_t)255; return q; };
  ushort* Bch = (ushort*)carve((size_t)512 * 2048 * 2);
  ushort* Bcl = (ushort*)carve((size_t)512 * 2048 * 2);
  ushort* zTh = (ushort*)carve((size_t)32768 * 128 * 2);
  ushort* zTl = (ushort*)carve((size_t)32768 * 128 * 2);
  ushort* Gh  = (ushort*)carve((size_t)8192 * 2048 * 2);
  ushort* Gl  = (ushort*)carve((size_t)8192 * 2048 * 2);
  float*  G0T = (float*)carve((size_t)32768 * 128 * 4);
  float*  P   = (float*)carve((size_t)2 * 4194304 * 4);   // 32MB: ru1 2x / ru2 4x partials
  float*  U   = (float*)carve((size_t)2097152 * 4);
  float*  h0  = (float*)carve((size_t)2097152 * 4);
  float*  h1  = (float*)carve((size_t)2097152 * 4);
  float*  ybuf = (float*)carve((size_t)B_ * N_ * 4);
  ushort* Wgh[4]; ushort* Wgl[4]; ushort* Wch[4]; ushort* Wcl[4];
  for (int c = 0; c < 4; ++c) {
    Wgh[c] = (ushort*)carve((size_t)640 * 128 * 2);
    Wgl[c] = (ushort*)carve((size_t)640 * 128 * 2);
    Wch[c] = (ushort*)carve((size_t)384 * 128 * 2);
    Wcl[c] = (ushort*)carve((size_t)384 * 128 * 2);
  }
  float* SSbuf = (float*)U;      // SS only needed during prep

  hipMemsetAsync(h0, 0, (size_t)2097152 * 4, stream);
  hipMemsetAsync(h1, 0, (size_t)2097152 * 4, stream);
  hipMemsetAsync(ybuf, 0, (size_t)B_ * N_ * 4, stream);

  ssq_k<<<dim3(32, 32, 2), dim3(16, 16), 0, stream>>>(supports, SSbuf);
  bcat_k<<<(512 * 2048 + 255) / 256, 256, 0, stream>>>(supports, SSbuf, Bch, Bcl);
  const int Cs[4] = { 66, 128, 65, 128 };
  for (int c = 0; c < 4; ++c) {
    wprep2_k<<<(640 * 128 + 255) / 256, 256, 0, stream>>>(Wg[c], Wgh[c], Wgl[c], Cs[c], 128, 640);
    wprep2_k<<<(384 * 128 + 255) / 256, 256, 0, stream>>>(Wc[c], Wch[c], Wcl[c], Cs[c], 64, 384);
  }

  auto cell = [&](int ci, int Cx, const float* x, int xmode, int t, float* h) {
    int C = Cx + 64;
    int K1 = (C + 31) & ~31;   // 96 or 128
    packzT_k<<<128, 256, 0, stream>>>(x, xmode, t, Cx, C, h, zTh, zTl);
    g1_k<0><<<dim3(256, 5), 256, 0, stream>>>(Wgh[ci], Wgl[ci], zTh, zTl, Gh, Gl, G0T, K1, 640);
    ru1g_k<<<dim3(64, 4, 2), 256, 0, stream>>>(Gh, Gl, Bch, Bcl, P);
    ru1f_k<<<4096, 256, 0, stream>>>(P, G0T, Bg[ci], h, U, zTh, zTl, Cx);
    g1_k<1><<<dim3(256, 3), 256, 0, stream>>>(Wch[ci], Wcl[ci], zTh, zTl, Gh, Gl, G0T, K1, 320);
    ru2g_k<<<dim3(32, 4, 4), 256, 0, stream>>>(Gh, Gl, Bch, Bcl, P);
    ru2f_k<<<2048, 256, 0, stream>>>(P, G0T, Bc[ci], U, h);
  };

  for (int t = 0; t < 12; ++t) {
    cell(0, 2, inputs, 0, t, h0);
    cell(1, 64, h0, 2, 0, h1);
  }
  for (int k = 0; k < 12; ++k) {
    cell(2, 1, ybuf, 1, 0, h0);
    cell(3, 64, h0, 2, 0, h1);
    proj_out_k<<<(B_ * N_ + 255) / 256, 256, 0, stream>>>(h1, proj_w, proj_b, ybuf, out, k);
  }
}

// Round 10
// 8292.603 us; speedup vs baseline: 1.8007x; 1.1452x over previous
//
#include <hip/hip_runtime.h>

#define B_ 64
#define N_ 512

typedef __attribute__((ext_vector_type(8))) short bf8_t;    // 8 bf16 (4 VGPRs)
typedef __attribute__((ext_vector_type(16))) float f16_t;   // 32x32 MFMA acc
typedef __attribute__((ext_vector_type(4))) float f4v_t;

#define MFMA32(a, b, c) __builtin_amdgcn_mfma_f32_32x32x16_bf16(a, b, c, 0, 0, 0)

__device__ __forceinline__ ushort f2bf(float x) {
  union { float f; unsigned u; } v; v.f = x;
  unsigned r = v.u + 0x7FFFu + ((v.u >> 16) & 1u);   // RNE
  return (ushort)(r >> 16);
}
__device__ __forceinline__ float bf2f(ushort h) {
  union { unsigned u; float f; } v; v.u = ((unsigned)h) << 16;
  return v.f;
}

__device__ __forceinline__ void gld16(const ushort* g, ushort* l) {
  __builtin_amdgcn_global_load_lds(
      (const __attribute__((address_space(1))) unsigned int*)(uintptr_t)g,
      (__attribute__((address_space(3))) unsigned int*)(uintptr_t)l,
      16, 0, 0);
}

// XCD-aware bijective swizzle (kept from R9; ~neutral but free)
__device__ __forceinline__ int xcd_logical(int nwg) {
  int lin = blockIdx.x + gridDim.x * (blockIdx.y + gridDim.y * blockIdx.z);
  return (lin & 7) * (nwg >> 3) + (lin >> 3);
}

// XOR swizzle (BK=32: 4x 16B slots/row; (r>>1)&3 spread → 2-way = free)
__device__ __forceinline__ int swz32(int r) { return (r >> 1) & 3; }

template <int ROWS, int THREADS>
__device__ __forceinline__ void stage_tile2(const ushort* g, int lda, int k0,
                                            ushort* l, int tid) {
  constexpr int RT = (ROWS * 32) / (THREADS * 8);
#pragma unroll
  for (int q = 0; q < RT; ++q) {
    int e  = q * THREADS * 8 + tid * 8;
    int r  = e >> 5;
    int c8 = (e >> 3) & 3;
    int g8 = c8 ^ swz32(r);
    gld16(g + (size_t)r * lda + k0 + g8 * 8, l + e);
  }
}

// ---------------------------------------------------------------------------
// 4-tile split-bf16 core (3-term): used by g1 (full precision, small K).
// ---------------------------------------------------------------------------
__device__ __forceinline__ void core128(
    const ushort* Ah, const ushort* Al, int lda,
    const ushort* Bh, const ushort* Bl, int ldb,
    int K, ushort* lds, f16_t acc[2][2]) {
  constexpr int TILE = 128 * 32;
  constexpr int SSZ  = 4 * TILE;
  const int tid = threadIdx.x, lane = tid & 63, wave = tid >> 6;
  const int ar = lane & 31, hb = lane >> 5;
  const int wm = wave >> 1, wn = wave & 1;

  auto stage = [&](int buf, int k0) {
    ushort* lb = lds + buf * SSZ;
    stage_tile2<128, 256>(Ah, lda, k0, lb, tid);
    stage_tile2<128, 256>(Al, lda, k0, lb + TILE, tid);
    stage_tile2<128, 256>(Bh, ldb, k0, lb + 2 * TILE, tid);
    stage_tile2<128, 256>(Bl, ldb, k0, lb + 3 * TILE, tid);
  };

  const int nc = K >> 5;
  stage(0, 0);
  int buf = 0;
  for (int c = 0; c < nc; ++c) {
    __syncthreads();
    if (c + 1 < nc) stage(buf ^ 1, (c + 1) << 5);
    const ushort* lb = lds + buf * SSZ;
#pragma unroll
    for (int ks = 0; ks < 2; ++ks) {
      bf8_t ah[2], al[2], bh[2], bl[2];
#pragma unroll
      for (int i = 0; i < 2; ++i) {
        int r = wm * 64 + 32 * i + ar;
        int c8 = (ks * 2 + hb) ^ swz32(r);
        ah[i] = *(const bf8_t*)(lb + r * 32 + c8 * 8);
        al[i] = *(const bf8_t*)(lb + TILE + r * 32 + c8 * 8);
      }
#pragma unroll
      for (int j = 0; j < 2; ++j) {
        int r = wn * 64 + 32 * j + ar;
        int c8 = (ks * 2 + hb) ^ swz32(r);
        bh[j] = *(const bf8_t*)(lb + 2 * TILE + r * 32 + c8 * 8);
        bl[j] = *(const bf8_t*)(lb + 3 * TILE + r * 32 + c8 * 8);
      }
#pragma unroll
      for (int i = 0; i < 2; ++i)
#pragma unroll
        for (int j = 0; j < 2; ++j) {
          acc[i][j] = MFMA32(ah[i], bh[j], acc[i][j]);
          acc[i][j] = MFMA32(ah[i], bl[j], acc[i][j]);
          acc[i][j] = MFMA32(al[i], bh[j], acc[i][j]);
        }
    }
    buf ^= 1;
  }
}

// ---------------------------------------------------------------------------
// 3-tile core (2-term): A = supports hi+lo (full precision), B = G bf16 single.
// (Ah+Al)*Bh. 48KB LDS -> 3 blocks/CU. Used by ru1g/ru2g.
// ---------------------------------------------------------------------------
__device__ __forceinline__ void core128_3(
    const ushort* Ah, const ushort* Al, int lda,
    const ushort* Bh, int ldb,
    int K, ushort* lds, f16_t acc[2][2]) {
  constexpr int TILE = 128 * 32;
  constexpr int SSZ  = 3 * TILE;
  const int tid = threadIdx.x, lane = tid & 63, wave = tid >> 6;
  const int ar = lane & 31, hb = lane >> 5;
  const int wm = wave >> 1, wn = wave & 1;

  auto stage = [&](int buf, int k0) {
    ushort* lb = lds + buf * SSZ;
    stage_tile2<128, 256>(Ah, lda, k0, lb, tid);
    stage_tile2<128, 256>(Al, lda, k0, lb + TILE, tid);
    stage_tile2<128, 256>(Bh, ldb, k0, lb + 2 * TILE, tid);
  };

  const int nc = K >> 5;
  stage(0, 0);
  int buf = 0;
  for (int c = 0; c < nc; ++c) {
    __syncthreads();
    if (c + 1 < nc) stage(buf ^ 1, (c + 1) << 5);
    const ushort* lb = lds + buf * SSZ;
#pragma unroll
    for (int ks = 0; ks < 2; ++ks) {
      bf8_t ah[2], al[2], bh[2];
#pragma unroll
      for (int i = 0; i < 2; ++i) {
        int r = wm * 64 + 32 * i + ar;
        int c8 = (ks * 2 + hb) ^ swz32(r);
        ah[i] = *(const bf8_t*)(lb + r * 32 + c8 * 8);
        al[i] = *(const bf8_t*)(lb + TILE + r * 32 + c8 * 8);
      }
#pragma unroll
      for (int j = 0; j < 2; ++j) {
        int r = wn * 64 + 32 * j + ar;
        int c8 = (ks * 2 + hb) ^ swz32(r);
        bh[j] = *(const bf8_t*)(lb + 2 * TILE + r * 32 + c8 * 8);
      }
#pragma unroll
      for (int i = 0; i < 2; ++i)
#pragma unroll
        for (int j = 0; j < 2; ++j) {
          acc[i][j] = MFMA32(ah[i], bh[j], acc[i][j]);
          acc[i][j] = MFMA32(al[i], bh[j], acc[i][j]);
        }
    }
    buf ^= 1;
  }
}

// C/D row-within-frag for 32x32: (r&3) + 8*(r>>2) + 4*hb
__device__ __forceinline__ int crow32(int r, int hb) {
  return (r & 3) + 8 * (r >> 2) + 4 * hb;
}

// ---------------------------------------------------------------------------
// Prep
// ---------------------------------------------------------------------------
__global__ __launch_bounds__(256) void ssq_k(const float* __restrict__ S,
                                             float* __restrict__ SS) {
  int s = blockIdx.z;
  const float* Ss = S + s * N_ * N_;
  __shared__ float Ta[16][17], Tb[16][17];
  int n = blockIdx.y * 16 + threadIdx.y;
  int m = blockIdx.x * 16 + threadIdx.x;
  float acc = 0.f;
  for (int p0 = 0; p0 < N_; p0 += 16) {
    Ta[threadIdx.y][threadIdx.x] = Ss[n * N_ + p0 + threadIdx.x];
    Tb[threadIdx.y][threadIdx.x] = Ss[(p0 + threadIdx.y) * N_ + m];
    __syncthreads();
#pragma unroll
    for (int pp = 0; pp < 16; ++pp)
      acc = fmaf(Ta[threadIdx.y][pp], Tb[pp][threadIdx.x], acc);
    __syncthreads();
  }
  SS[((size_t)s * N_ + n) * N_ + m] = acc;
}

// Bcat[n][k], k = seg*512+m, segs [S0, S0^2, S1, S1^2], split hi/lo
__global__ __launch_bounds__(256) void bcat_k(const float* __restrict__ S,
                                              const float* __restrict__ SS,
                                              ushort* __restrict__ Bh,
                                              ushort* __restrict__ Bl) {
  int idx = blockIdx.x * 256 + threadIdx.x;
  if (idx >= 512 * 2048) return;
  int k = idx & 2047, n = idx >> 11;
  int seg = k >> 9, m = k & 511;
  float v;
  if (seg == 0)      v = S[(size_t)n * 512 + m];
  else if (seg == 1) v = SS[(size_t)n * 512 + m];
  else if (seg == 2) v = S[(size_t)(512 + n) * 512 + m];
  else               v = SS[(size_t)(512 + n) * 512 + m];
  ushort hh = f2bf(v);
  Bh[idx] = hh; Bl[idx] = f2bf(v - bf2f(hh));
}

// Wt[i = t*Dout + d][c] (128-wide rows) from W[(t*C+c)*Dout + d]; zeros outside
__global__ __launch_bounds__(256) void wprep2_k(const float* __restrict__ W,
                                                ushort* __restrict__ Wh,
                                                ushort* __restrict__ Wl,
                                                int C, int Dout, int Mt) {
  int idx = blockIdx.x * 256 + threadIdx.x;
  if (idx >= Mt * 128) return;
  int c = idx & 127, i = idx >> 7;
  int t = i / Dout, d = i % Dout;
  float v = (c < C && t < 5) ? W[(size_t)(t * C + c) * Dout + d] : 0.f;
  ushort hh = f2bf(v);
  Wh[idx] = hh; Wl[idx] = f2bf(v - bf2f(hh));
}

// ---------------------------------------------------------------------------
// Pack zT[(b,n)][c] = [x | h | 0-pad], split hi/lo. hT is [(b,n)][d].
// xmode 0: inputs gather (t); xmode 1: flat [jg]; xmode 2: hT-row layout
// ---------------------------------------------------------------------------
__global__ __launch_bounds__(256) void packzT_k(const float* __restrict__ xsrc,
                                                int xmode, int t, int Cx, int C,
                                                const float* __restrict__ hT,
                                                ushort* __restrict__ Zh,
                                                ushort* __restrict__ Zl) {
  int jg = blockIdx.x * 256 + threadIdx.x;   // b*512 + n
  int b = jg >> 9, n = jg & 511;
  for (int c0 = 0; c0 < 128; c0 += 8) {
    bf8_t vh, vl;
#pragma unroll
    for (int q = 0; q < 8; ++q) {
      int c = c0 + q;
      float v;
      if (c < Cx) {
        if (xmode == 0)      v = xsrc[((size_t)(b * Cx + c) * 512 + n) * 12 + t];
        else if (xmode == 1) v = xsrc[jg];
        else                 v = xsrc[(size_t)jg * 64 + c];
      } else if (c < C) {
        v = hT[(size_t)jg * 64 + (c - Cx)];
      } else {
        v = 0.f;
      }
      ushort hh = f2bf(v);
      vh[q] = (short)hh;
      vl[q] = (short)f2bf(v - bf2f(hh));
    }
    *(bf8_t*)(Zh + (size_t)jg * 128 + c0) = vh;
    *(bf8_t*)(Zl + (size_t)jg * 128 + c0) = vl;
  }
}

// ---------------------------------------------------------------------------
// Step 1: G = Wt * zT^T (full 3-term). t=0 -> f32 G0T; t>=1 -> Gh bf16 only.
// MODE 0: DR=128 (gate, NMT=5); MODE 1: DR=64 (cand, NMT=3)
// ---------------------------------------------------------------------------
template <int MODE>
__global__ __launch_bounds__(256, 2) void g1_k(const ushort* __restrict__ Wh,
                                               const ushort* __restrict__ Wl,
                                               const ushort* __restrict__ Zh,
                                               const ushort* __restrict__ Zl,
                                               ushort* __restrict__ Gh,
                                               float* __restrict__ G0T,
                                               int K, int Mlimit) {
  __shared__ __attribute__((aligned(16))) ushort lds[2 * 4 * 128 * 32];
  constexpr int DR = (MODE == 0) ? 128 : 64;
  constexpr int NMT = (MODE == 0) ? 5 : 3;
  int tid = threadIdx.x, lane = tid & 63, wave = tid >> 6;
  int wm = wave >> 1, wn = wave & 1, ar = lane & 31, hb = lane >> 5;
  int L = xcd_logical(256 * NMT);
  int mt = L % NMT, nt = L / NMT;
  f16_t acc[2][2] = {};
  core128(Wh + (size_t)mt * 128 * 128, Wl + (size_t)mt * 128 * 128, 128,
          Zh + (size_t)nt * 128 * 128, Zl + (size_t)nt * 128 * 128, 128,
          K, lds, acc);
#pragma unroll
  for (int i = 0; i < 2; ++i)
#pragma unroll
    for (int j = 0; j < 2; ++j) {
      int jg = nt * 128 + wn * 64 + 32 * j + ar;   // b*512 + m
      int b = jg >> 9, m = jg & 511;
#pragma unroll
      for (int r = 0; r < 16; ++r) {
        int ii = mt * 128 + wm * 64 + 32 * i + crow32(r, hb);
        if (ii >= Mlimit) continue;
        float v = acc[i][j][r];
        int t = ii / DR, d = ii % DR;
        if (t == 0) {
          G0T[(size_t)jg * DR + d] = v;
        } else {
          Gh[((size_t)(b * DR + d)) * 2048 + (size_t)(t - 1) * 512 + m] = f2bf(v);
        }
      }
    }
}

// ---------------------------------------------------------------------------
// Gate diffusion GEMM (2-term, 3-tile), split-K kz=2: partials -> P
// ---------------------------------------------------------------------------
__global__ __launch_bounds__(256, 3) void ru1g_k(const ushort* __restrict__ Gh,
                                                 const ushort* __restrict__ Bch,
                                                 const ushort* __restrict__ Bcl,
                                                 float* __restrict__ P) {
  __shared__ __attribute__((aligned(16))) ushort lds[2 * 3 * 128 * 32];
  int tid = threadIdx.x, lane = tid & 63, wave = tid >> 6;
  int wm = wave >> 1, wn = wave & 1, ar = lane & 31, hb = lane >> 5;
  int L = xcd_logical(512);
  int mt = L & 3, nt = (L >> 2) & 63, kz = L >> 8;
  f16_t acc[2][2] = {};
  core128_3(Bch + (size_t)mt * 128 * 2048 + kz * 1024,
            Bcl + (size_t)mt * 128 * 2048 + kz * 1024, 2048,
            Gh + (size_t)nt * 128 * 2048 + kz * 1024, 2048,
            1024, lds, acc);
  float* Pz = P + (size_t)kz * 4194304;
#pragma unroll
  for (int i = 0; i < 2; ++i)
#pragma unroll
    for (int j = 0; j < 2; ++j) {
      int R = nt * 128 + wn * 64 + 32 * j + ar;
      int b = R >> 7, d = R & 127;
#pragma unroll
      for (int r = 0; r < 16; ++r) {
        int node = mt * 128 + wm * 64 + 32 * i + crow32(r, hb);
        Pz[((size_t)b * 512 + node) * 128 + d] = acc[i][j][r];
      }
    }
}

// finish gate: sigmoid(P0+P1+G0T+bg); d<64 -> r*h into zT; d>=64 -> u into U
__global__ __launch_bounds__(256) void ru1f_k(const float* __restrict__ P,
                                              const float* __restrict__ G0T,
                                              const float* __restrict__ bg,
                                              const float* __restrict__ hT,
                                              float* __restrict__ U,
                                              ushort* __restrict__ Zh,
                                              ushort* __restrict__ Zl, int Cx) {
  int i4 = blockIdx.x * 256 + threadIdx.x;
  if (i4 >= 1048576) return;
  int base = i4 * 4;
  int row = base >> 7, d = base & 127;
  f4v_t p0 = *(const f4v_t*)(P + base);
  f4v_t p1 = *(const f4v_t*)(P + 4194304 + base);
  f4v_t g0 = *(const f4v_t*)(G0T + base);
  if (d < 64) {
    f4v_t hv = *(const f4v_t*)(hT + (size_t)row * 64 + d);
#pragma unroll
    for (int e = 0; e < 4; ++e) {
      float s = 1.f / (1.f + expf(-(p0[e] + p1[e] + g0[e] + bg[d + e])));
      float rh = s * hv[e];
      ushort hh = f2bf(rh);
      Zh[(size_t)row * 128 + Cx + d + e] = hh;
      Zl[(size_t)row * 128 + Cx + d + e] = f2bf(rh - bf2f(hh));
    }
  } else {
    f4v_t uo;
#pragma unroll
    for (int e = 0; e < 4; ++e)
      uo[e] = 1.f / (1.f + expf(-(p0[e] + p1[e] + g0[e] + bg[d + e])));
    *(f4v_t*)(U + (size_t)row * 64 + (d - 64)) = uo;
  }
}

// ---------------------------------------------------------------------------
// Cand diffusion GEMM (2-term, 3-tile), split-K kz=4.
// ---------------------------------------------------------------------------
__global__ __launch_bounds__(256, 3) void ru2g_k(const ushort* __restrict__ Gh,
                                                 const ushort* __restrict__ Bch,
                                                 const ushort* __restrict__ Bcl,
                                                 float* __restrict__ P) {
  __shared__ __attribute__((aligned(16))) ushort lds[2 * 3 * 128 * 32];
  int tid = threadIdx.x, lane = tid & 63, wave = tid >> 6;
  int wm = wave >> 1, wn = wave & 1, ar = lane & 31, hb = lane >> 5;
  int L = xcd_logical(512);
  int mt = L & 3, nt = (L >> 2) & 31, kz = L >> 7;
  f16_t acc[2][2] = {};
  core128_3(Bch + (size_t)mt * 128 * 2048 + kz * 512,
            Bcl + (size_t)mt * 128 * 2048 + kz * 512, 2048,
            Gh + (size_t)nt * 128 * 2048 + kz * 512, 2048,
            512, lds, acc);
  float* Pz = P + (size_t)kz * 2097152;
#pragma unroll
  for (int i = 0; i < 2; ++i)
#pragma unroll
    for (int j = 0; j < 2; ++j) {
      int R = nt * 128 + wn * 64 + 32 * j + ar;
      int b = R >> 6, d = R & 63;
#pragma unroll
      for (int r = 0; r < 16; ++r) {
        int node = mt * 128 + wm * 64 + 32 * i + crow32(r, hb);
        Pz[((size_t)b * 512 + node) * 64 + d] = acc[i][j][r];
      }
    }
}

// finish cand: c~ = tanh(sum P + G0c + bc); h = u*h + (1-u)*c~
__global__ __launch_bounds__(256) void ru2f_k(const float* __restrict__ P,
                                              const float* __restrict__ G0c,
                                              const float* __restrict__ bc,
                                              const float* __restrict__ U,
                                              float* __restrict__ hT) {
  int i4 = blockIdx.x * 256 + threadIdx.x;
  if (i4 >= 524288) return;
  int base = i4 * 4;
  int d = base & 63;
  f4v_t p0 = *(const f4v_t*)(P + base);
  f4v_t p1 = *(const f4v_t*)(P + 2097152 + base);
  f4v_t p2 = *(const f4v_t*)(P + 2 * 2097152 + base);
  f4v_t p3 = *(const f4v_t*)(P + 3 * 2097152 + base);
  f4v_t g0 = *(const f4v_t*)(G0c + base);
  f4v_t uv = *(const f4v_t*)(U + base);
  f4v_t hv = *(const f4v_t*)(hT + base);
#pragma unroll
  for (int e = 0; e < 4; ++e) {
    float ct = tanhf(p0[e] + p1[e] + p2[e] + p3[e] + g0[e] + bc[d + e]);
    hv[e] = uv[e] * hv[e] + (1.f - uv[e]) * ct;
  }
  *(f4v_t*)(hT + base) = hv;
}

__global__ __launch_bounds__(256) void proj_out_k(const float* __restrict__ h1T,
                                                  const float* __restrict__ pw,
                                                  const float* __restrict__ pb,
                                                  float* __restrict__ ybuf,
                                                  float* __restrict__ out, int k) {
  int idx = blockIdx.x * blockDim.x + threadIdx.x;
  if (idx >= B_ * N_) return;
  float s = pb[0];
  const float* hrow = h1T + (size_t)idx * 64;
#pragma unroll
  for (int j = 0; j < 64; ++j)
    s = fmaf(pw[j], hrow[j], s);
  ybuf[idx] = s;
  out[(size_t)idx * 12 + k] = s;
}

extern "C" void kernel_launch(void* const* d_in, const int* in_sizes, int n_in,
                              void* d_out, int out_size, void* d_ws, size_t ws_size,
                              hipStream_t stream) {
  const float* inputs   = (const float*)d_in[0];
  const float* supports = (const float*)d_in[1];
  const float* Wg[4] = { (const float*)d_in[2],  (const float*)d_in[6],
                         (const float*)d_in[10], (const float*)d_in[14] };
  const float* Bg[4] = { (const float*)d_in[3],  (const float*)d_in[7],
                         (const float*)d_in[11], (const float*)d_in[15] };
  const float* Wc[4] = { (const float*)d_in[4],  (const float*)d_in[8],
                         (const float*)d_in[12], (const float*)d_in[16] };
  const float* Bc[4] = { (const float*)d_in[5],  (const float*)d_in[9],
                         (const float*)d_in[13], (const float*)d_in[17] };
  const float* proj_w = (const float*)d_in[18];
  const float* proj_b = (const float*)d_in[19];
  float* out = (float*)d_out;

  char* p = (char*)d_ws;
  auto carve = [&](size_t bytes) { void* q = p; p += (bytes + 255) & ~(size_t)255; return q; };
  ushort* Bch = (ushort*)carve((size_t)512 * 2048 * 2);
  ushort* Bcl = (ushort*)carve((size_t)512 * 2048 * 2);
  ushort* zTh = (ushort*)carve((size_t)32768 * 128 * 2);
  ushort* zTl = (ushort*)carve((size_t)32768 * 128 * 2);
  ushort* Gh  = (ushort*)carve((size_t)8192 * 2048 * 2);
  float*  G0T = (float*)carve((size_t)32768 * 128 * 4);
  float*  P   = (float*)carve((size_t)2 * 4194304 * 4);   // 32MB: ru1 2x / ru2 4x partials
  float*  U   = (float*)carve((size_t)2097152 * 4);
  float*  h0  = (float*)carve((size_t)2097152 * 4);
  float*  h1  = (float*)carve((size_t)2097152 * 4);
  float*  ybuf = (float*)carve((size_t)B_ * N_ * 4);
  ushort* Wgh[4]; ushort* Wgl[4]; ushort* Wch[4]; ushort* Wcl[4];
  for (int c = 0; c < 4; ++c) {
    Wgh[c] = (ushort*)carve((size_t)640 * 128 * 2);
    Wgl[c] = (ushort*)carve((size_t)640 * 128 * 2);
    Wch[c] = (ushort*)carve((size_t)384 * 128 * 2);
    Wcl[c] = (ushort*)carve((size_t)384 * 128 * 2);
  }
  float* SSbuf = (float*)U;      // SS only needed during prep

  hipMemsetAsync(h0, 0, (size_t)2097152 * 4, stream);
  hipMemsetAsync(h1, 0, (size_t)2097152 * 4, stream);
  hipMemsetAsync(ybuf, 0, (size_t)B_ * N_ * 4, stream);

  ssq_k<<<dim3(32, 32, 2), dim3(16, 16), 0, stream>>>(supports, SSbuf);
  bcat_k<<<(512 * 2048 + 255) / 256, 256, 0, stream>>>(supports, SSbuf, Bch, Bcl);
  const int Cs[4] = { 66, 128, 65, 128 };
  for (int c = 0; c < 4; ++c) {
    wprep2_k<<<(640 * 128 + 255) / 256, 256, 0, stream>>>(Wg[c], Wgh[c], Wgl[c], Cs[c], 128, 640);
    wprep2_k<<<(384 * 128 + 255) / 256, 256, 0, stream>>>(Wc[c], Wch[c], Wcl[c], Cs[c], 64, 384);
  }

  auto cell = [&](int ci, int Cx, const float* x, int xmode, int t, float* h) {
    int C = Cx + 64;
    int K1 = (C + 31) & ~31;   // 96 or 128
    packzT_k<<<128, 256, 0, stream>>>(x, xmode, t, Cx, C, h, zTh, zTl);
    g1_k<0><<<dim3(256, 5), 256, 0, stream>>>(Wgh[ci], Wgl[ci], zTh, zTl, Gh, G0T, K1, 640);
    ru1g_k<<<dim3(64, 4, 2), 256, 0, stream>>>(Gh, Bch, Bcl, P);
    ru1f_k<<<4096, 256, 0, stream>>>(P, G0T, Bg[ci], h, U, zTh, zTl, Cx);
    g1_k<1><<<dim3(256, 3), 256, 0, stream>>>(Wch[ci], Wcl[ci], zTh, zTl, Gh, G0T, K1, 320);
    ru2g_k<<<dim3(32, 4, 4), 256, 0, stream>>>(Gh, Bch, Bcl, P);
    ru2f_k<<<2048, 256, 0, stream>>>(P, G0T, Bc[ci], U, h);
  };

  for (int t = 0; t < 12; ++t) {
    cell(0, 2, inputs, 0, t, h0);
    cell(1, 64, h0, 2, 0, h1);
  }
  for (int k = 0; k < 12; ++k) {
    cell(2, 1, ybuf, 1, 0, h0);
    cell(3, 64, h0, 2, 0, h1);
    proj_out_k<<<(B_ * N_ + 255) / 256, 256, 0, stream>>>(h1, proj_w, proj_b, ybuf, out, k);
  }
}

// Round 11
// 7690.567 us; speedup vs baseline: 1.9417x; 1.0783x over previous
//
#include <hip/hip_runtime.h>

#define B_ 64
#define N_ 512

typedef __attribute__((ext_vector_type(8))) short bf8_t;    // 8 bf16 (4 VGPRs)
typedef __attribute__((ext_vector_type(16))) float f16_t;   // 32x32 MFMA acc
typedef __attribute__((ext_vector_type(4))) float f4v_t;

#define MFMA32(a, b, c) __builtin_amdgcn_mfma_f32_32x32x16_bf16(a, b, c, 0, 0, 0)

__device__ __forceinline__ ushort f2bf(float x) {
  union { float f; unsigned u; } v; v.f = x;
  unsigned r = v.u + 0x7FFFu + ((v.u >> 16) & 1u);   // RNE
  return (ushort)(r >> 16);
}
__device__ __forceinline__ float bf2f(ushort h) {
  union { unsigned u; float f; } v; v.u = ((unsigned)h) << 16;
  return v.f;
}

__device__ __forceinline__ void gld16(const ushort* g, ushort* l) {
  __builtin_amdgcn_global_load_lds(
      (const __attribute__((address_space(1))) unsigned int*)(uintptr_t)g,
      (__attribute__((address_space(3))) unsigned int*)(uintptr_t)l,
      16, 0, 0);
}

// XCD-aware bijective swizzle
__device__ __forceinline__ int xcd_logical(int nwg) {
  int lin = blockIdx.x + gridDim.x * (blockIdx.y + gridDim.y * blockIdx.z);
  return (lin & 7) * (nwg >> 3) + (lin >> 3);
}

// XOR swizzle (BK=32: 4x 16B slots/row; (r>>1)&3 spread → 2-way = free)
__device__ __forceinline__ int swz32(int r) { return (r >> 1) & 3; }

template <int ROWS, int THREADS>
__device__ __forceinline__ void stage_tile2(const ushort* g, int lda, int k0,
                                            ushort* l, int tid) {
  constexpr int RT = (ROWS * 32) / (THREADS * 8);
#pragma unroll
  for (int q = 0; q < RT; ++q) {
    int e  = q * THREADS * 8 + tid * 8;
    int r  = e >> 5;
    int c8 = (e >> 3) & 3;
    int g8 = c8 ^ swz32(r);
    gld16(g + (size_t)r * lda + k0 + g8 * 8, l + e);
  }
}

// ---------------------------------------------------------------------------
// 4-tile split-bf16 core (3-term): used by g1 (full precision, small K).
// ---------------------------------------------------------------------------
__device__ __forceinline__ void core128(
    const ushort* Ah, const ushort* Al, int lda,
    const ushort* Bh, const ushort* Bl, int ldb,
    int K, ushort* lds, f16_t acc[2][2]) {
  constexpr int TILE = 128 * 32;
  constexpr int SSZ  = 4 * TILE;
  const int tid = threadIdx.x, lane = tid & 63, wave = tid >> 6;
  const int ar = lane & 31, hb = lane >> 5;
  const int wm = wave >> 1, wn = wave & 1;

  auto stage = [&](int buf, int k0) {
    ushort* lb = lds + buf * SSZ;
    stage_tile2<128, 256>(Ah, lda, k0, lb, tid);
    stage_tile2<128, 256>(Al, lda, k0, lb + TILE, tid);
    stage_tile2<128, 256>(Bh, ldb, k0, lb + 2 * TILE, tid);
    stage_tile2<128, 256>(Bl, ldb, k0, lb + 3 * TILE, tid);
  };

  const int nc = K >> 5;
  stage(0, 0);
  int buf = 0;
  for (int c = 0; c < nc; ++c) {
    __syncthreads();
    if (c + 1 < nc) stage(buf ^ 1, (c + 1) << 5);
    const ushort* lb = lds + buf * SSZ;
#pragma unroll
    for (int ks = 0; ks < 2; ++ks) {
      bf8_t ah[2], al[2], bh[2], bl[2];
#pragma unroll
      for (int i = 0; i < 2; ++i) {
        int r = wm * 64 + 32 * i + ar;
        int c8 = (ks * 2 + hb) ^ swz32(r);
        ah[i] = *(const bf8_t*)(lb + r * 32 + c8 * 8);
        al[i] = *(const bf8_t*)(lb + TILE + r * 32 + c8 * 8);
      }
#pragma unroll
      for (int j = 0; j < 2; ++j) {
        int r = wn * 64 + 32 * j + ar;
        int c8 = (ks * 2 + hb) ^ swz32(r);
        bh[j] = *(const bf8_t*)(lb + 2 * TILE + r * 32 + c8 * 8);
        bl[j] = *(const bf8_t*)(lb + 3 * TILE + r * 32 + c8 * 8);
      }
#pragma unroll
      for (int i = 0; i < 2; ++i)
#pragma unroll
        for (int j = 0; j < 2; ++j) {
          acc[i][j] = MFMA32(ah[i], bh[j], acc[i][j]);
          acc[i][j] = MFMA32(ah[i], bl[j], acc[i][j]);
          acc[i][j] = MFMA32(al[i], bh[j], acc[i][j]);
        }
    }
    buf ^= 1;
  }
}

// ---------------------------------------------------------------------------
// 2-tile core (1-term pure bf16): A = Bcat hi, B = G. 32KB LDS dbuf.
// Row-stochastic averaging washes the dropped lo-terms (see R10/R11 analysis).
// ---------------------------------------------------------------------------
__device__ __forceinline__ void core128_1(
    const ushort* Ah, int lda,
    const ushort* Bh, int ldb,
    int K, ushort* lds, f16_t acc[2][2]) {
  constexpr int TILE = 128 * 32;
  constexpr int SSZ  = 2 * TILE;
  const int tid = threadIdx.x, lane = tid & 63, wave = tid >> 6;
  const int ar = lane & 31, hb = lane >> 5;
  const int wm = wave >> 1, wn = wave & 1;

  auto stage = [&](int buf, int k0) {
    ushort* lb = lds + buf * SSZ;
    stage_tile2<128, 256>(Ah, lda, k0, lb, tid);
    stage_tile2<128, 256>(Bh, ldb, k0, lb + TILE, tid);
  };

  const int nc = K >> 5;
  stage(0, 0);
  int buf = 0;
  for (int c = 0; c < nc; ++c) {
    __syncthreads();
    if (c + 1 < nc) stage(buf ^ 1, (c + 1) << 5);
    const ushort* lb = lds + buf * SSZ;
#pragma unroll
    for (int ks = 0; ks < 2; ++ks) {
      bf8_t ah[2], bh[2];
#pragma unroll
      for (int i = 0; i < 2; ++i) {
        int r = wm * 64 + 32 * i + ar;
        int c8 = (ks * 2 + hb) ^ swz32(r);
        ah[i] = *(const bf8_t*)(lb + r * 32 + c8 * 8);
      }
#pragma unroll
      for (int j = 0; j < 2; ++j) {
        int r = wn * 64 + 32 * j + ar;
        int c8 = (ks * 2 + hb) ^ swz32(r);
        bh[j] = *(const bf8_t*)(lb + TILE + r * 32 + c8 * 8);
      }
#pragma unroll
      for (int i = 0; i < 2; ++i)
#pragma unroll
        for (int j = 0; j < 2; ++j)
          acc[i][j] = MFMA32(ah[i], bh[j], acc[i][j]);
    }
    buf ^= 1;
  }
}

// C/D row-within-frag for 32x32: (r&3) + 8*(r>>2) + 4*hb
__device__ __forceinline__ int crow32(int r, int hb) {
  return (r & 3) + 8 * (r >> 2) + 4 * hb;
}

// ---------------------------------------------------------------------------
// Prep
// ---------------------------------------------------------------------------
__global__ __launch_bounds__(256) void ssq_k(const float* __restrict__ S,
                                             float* __restrict__ SS) {
  int s = blockIdx.z;
  const float* Ss = S + s * N_ * N_;
  __shared__ float Ta[16][17], Tb[16][17];
  int n = blockIdx.y * 16 + threadIdx.y;
  int m = blockIdx.x * 16 + threadIdx.x;
  float acc = 0.f;
  for (int p0 = 0; p0 < N_; p0 += 16) {
    Ta[threadIdx.y][threadIdx.x] = Ss[n * N_ + p0 + threadIdx.x];
    Tb[threadIdx.y][threadIdx.x] = Ss[(p0 + threadIdx.y) * N_ + m];
    __syncthreads();
#pragma unroll
    for (int pp = 0; pp < 16; ++pp)
      acc = fmaf(Ta[threadIdx.y][pp], Tb[pp][threadIdx.x], acc);
    __syncthreads();
  }
  SS[((size_t)s * N_ + n) * N_ + m] = acc;
}

// Bcat[n][k] hi only, k = seg*512+m, segs [S0, S0^2, S1, S1^2]
__global__ __launch_bounds__(256) void bcat_k(const float* __restrict__ S,
                                              const float* __restrict__ SS,
                                              ushort* __restrict__ Bh) {
  int idx = blockIdx.x * 256 + threadIdx.x;
  if (idx >= 512 * 2048) return;
  int k = idx & 2047, n = idx >> 11;
  int seg = k >> 9, m = k & 511;
  float v;
  if (seg == 0)      v = S[(size_t)n * 512 + m];
  else if (seg == 1) v = SS[(size_t)n * 512 + m];
  else if (seg == 2) v = S[(size_t)(512 + n) * 512 + m];
  else               v = SS[(size_t)(512 + n) * 512 + m];
  Bh[idx] = f2bf(v);
}

// Wt[i = t*Dout + d][c] (128-wide rows) from W[(t*C+c)*Dout + d]; zeros outside
__global__ __launch_bounds__(256) void wprep2_k(const float* __restrict__ W,
                                                ushort* __restrict__ Wh,
                                                ushort* __restrict__ Wl,
                                                int C, int Dout, int Mt) {
  int idx = blockIdx.x * 256 + threadIdx.x;
  if (idx >= Mt * 128) return;
  int c = idx & 127, i = idx >> 7;
  int t = i / Dout, d = i % Dout;
  float v = (c < C && t < 5) ? W[(size_t)(t * C + c) * Dout + d] : 0.f;
  ushort hh = f2bf(v);
  Wh[idx] = hh; Wl[idx] = f2bf(v - bf2f(hh));
}

// ---------------------------------------------------------------------------
// Pack zT[(b,n)][c] = [x | h | 0-pad], split hi/lo. hT is [(b,n)][d].
// xmode 0: inputs gather (t); xmode 1: flat [jg]; xmode 2: hT-row layout
// ---------------------------------------------------------------------------
__global__ __launch_bounds__(256) void packzT_k(const float* __restrict__ xsrc,
                                                int xmode, int t, int Cx, int C,
                                                const float* __restrict__ hT,
                                                ushort* __restrict__ Zh,
                                                ushort* __restrict__ Zl) {
  int jg = blockIdx.x * 256 + threadIdx.x;   // b*512 + n
  int b = jg >> 9, n = jg & 511;
  for (int c0 = 0; c0 < 128; c0 += 8) {
    bf8_t vh, vl;
#pragma unroll
    for (int q = 0; q < 8; ++q) {
      int c = c0 + q;
      float v;
      if (c < Cx) {
        if (xmode == 0)      v = xsrc[((size_t)(b * Cx + c) * 512 + n) * 12 + t];
        else if (xmode == 1) v = xsrc[jg];
        else                 v = xsrc[(size_t)jg * 64 + c];
      } else if (c < C) {
        v = hT[(size_t)jg * 64 + (c - Cx)];
      } else {
        v = 0.f;
      }
      ushort hh = f2bf(v);
      vh[q] = (short)hh;
      vl[q] = (short)f2bf(v - bf2f(hh));
    }
    *(bf8_t*)(Zh + (size_t)jg * 128 + c0) = vh;
    *(bf8_t*)(Zl + (size_t)jg * 128 + c0) = vl;
  }
}

// ---------------------------------------------------------------------------
// Step 1: G = Wt * zT^T (full 3-term). t=0 -> f32 G0T; t>=1 -> Gh bf16 only.
// MODE 0: DR=128 (gate, NMT=5); MODE 1: DR=64 (cand, NMT=3)
// ---------------------------------------------------------------------------
template <int MODE>
__global__ __launch_bounds__(256, 2) void g1_k(const ushort* __restrict__ Wh,
                                               const ushort* __restrict__ Wl,
                                               const ushort* __restrict__ Zh,
                                               const ushort* __restrict__ Zl,
                                               ushort* __restrict__ Gh,
                                               float* __restrict__ G0T,
                                               int K, int Mlimit) {
  __shared__ __attribute__((aligned(16))) ushort lds[2 * 4 * 128 * 32];
  constexpr int DR = (MODE == 0) ? 128 : 64;
  constexpr int NMT = (MODE == 0) ? 5 : 3;
  int tid = threadIdx.x, lane = tid & 63, wave = tid >> 6;
  int wm = wave >> 1, wn = wave & 1, ar = lane & 31, hb = lane >> 5;
  int L = xcd_logical(256 * NMT);
  int mt = L % NMT, nt = L / NMT;
  f16_t acc[2][2] = {};
  core128(Wh + (size_t)mt * 128 * 128, Wl + (size_t)mt * 128 * 128, 128,
          Zh + (size_t)nt * 128 * 128, Zl + (size_t)nt * 128 * 128, 128,
          K, lds, acc);
#pragma unroll
  for (int i = 0; i < 2; ++i)
#pragma unroll
    for (int j = 0; j < 2; ++j) {
      int jg = nt * 128 + wn * 64 + 32 * j + ar;   // b*512 + m
      int b = jg >> 9, m = jg & 511;
#pragma unroll
      for (int r = 0; r < 16; ++r) {
        int ii = mt * 128 + wm * 64 + 32 * i + crow32(r, hb);
        if (ii >= Mlimit) continue;
        float v = acc[i][j][r];
        int t = ii / DR, d = ii % DR;
        if (t == 0) {
          G0T[(size_t)jg * DR + d] = v;
        } else {
          Gh[((size_t)(b * DR + d)) * 2048 + (size_t)(t - 1) * 512 + m] = f2bf(v);
        }
      }
    }
}

// ---------------------------------------------------------------------------
// Gate diffusion GEMM (1-term, 2-tile), split-K kz=3 (768/768/512): -> P
// grid 768 blocks (3/CU), 32KB LDS.
// ---------------------------------------------------------------------------
__global__ __launch_bounds__(256, 3) void ru1g_k(const ushort* __restrict__ Gh,
                                                 const ushort* __restrict__ Bch,
                                                 float* __restrict__ P) {
  __shared__ __attribute__((aligned(16))) ushort lds[2 * 2 * 128 * 32];
  int tid = threadIdx.x, lane = tid & 63, wave = tid >> 6;
  int wm = wave >> 1, wn = wave & 1, ar = lane & 31, hb = lane >> 5;
  int L = xcd_logical(768);
  int mt = L & 3, nt = (L >> 2) & 63, kz = L >> 8;   // kz 0..2
  int k0 = kz * 768;
  int K  = (kz == 2) ? 512 : 768;
  f16_t acc[2][2] = {};
  core128_1(Bch + (size_t)mt * 128 * 2048 + k0, 2048,
            Gh + (size_t)nt * 128 * 2048 + k0, 2048,
            K, lds, acc);
  float* Pz = P + (size_t)kz * 4194304;
#pragma unroll
  for (int i = 0; i < 2; ++i)
#pragma unroll
    for (int j = 0; j < 2; ++j) {
      int R = nt * 128 + wn * 64 + 32 * j + ar;
      int b = R >> 7, d = R & 127;
#pragma unroll
      for (int r = 0; r < 16; ++r) {
        int node = mt * 128 + wm * 64 + 32 * i + crow32(r, hb);
        Pz[((size_t)b * 512 + node) * 128 + d] = acc[i][j][r];
      }
    }
}

// finish gate: sigmoid(P0+P1+P2+G0T+bg); d<64 -> r*h into zT; d>=64 -> u into U
__global__ __launch_bounds__(256) void ru1f_k(const float* __restrict__ P,
                                              const float* __restrict__ G0T,
                                              const float* __restrict__ bg,
                                              const float* __restrict__ hT,
                                              float* __restrict__ U,
                                              ushort* __restrict__ Zh,
                                              ushort* __restrict__ Zl, int Cx) {
  int i4 = blockIdx.x * 256 + threadIdx.x;
  if (i4 >= 1048576) return;
  int base = i4 * 4;
  int row = base >> 7, d = base & 127;
  f4v_t p0 = *(const f4v_t*)(P + base);
  f4v_t p1 = *(const f4v_t*)(P + 4194304 + base);
  f4v_t p2 = *(const f4v_t*)(P + 2 * 4194304 + base);
  f4v_t g0 = *(const f4v_t*)(G0T + base);
  if (d < 64) {
    f4v_t hv = *(const f4v_t*)(hT + (size_t)row * 64 + d);
#pragma unroll
    for (int e = 0; e < 4; ++e) {
      float s = 1.f / (1.f + expf(-(p0[e] + p1[e] + p2[e] + g0[e] + bg[d + e])));
      float rh = s * hv[e];
      ushort hh = f2bf(rh);
      Zh[(size_t)row * 128 + Cx + d + e] = hh;
      Zl[(size_t)row * 128 + Cx + d + e] = f2bf(rh - bf2f(hh));
    }
  } else {
    f4v_t uo;
#pragma unroll
    for (int e = 0; e < 4; ++e)
      uo[e] = 1.f / (1.f + expf(-(p0[e] + p1[e] + p2[e] + g0[e] + bg[d + e])));
    *(f4v_t*)(U + (size_t)row * 64 + (d - 64)) = uo;
  }
}

// ---------------------------------------------------------------------------
// Cand diffusion GEMM (1-term, 2-tile), split-K kz=4.
// ---------------------------------------------------------------------------
__global__ __launch_bounds__(256, 3) void ru2g_k(const ushort* __restrict__ Gh,
                                                 const ushort* __restrict__ Bch,
                                                 float* __restrict__ P) {
  __shared__ __attribute__((aligned(16))) ushort lds[2 * 2 * 128 * 32];
  int tid = threadIdx.x, lane = tid & 63, wave = tid >> 6;
  int wm = wave >> 1, wn = wave & 1, ar = lane & 31, hb = lane >> 5;
  int L = xcd_logical(512);
  int mt = L & 3, nt = (L >> 2) & 31, kz = L >> 7;
  f16_t acc[2][2] = {};
  core128_1(Bch + (size_t)mt * 128 * 2048 + kz * 512, 2048,
            Gh + (size_t)nt * 128 * 2048 + kz * 512, 2048,
            512, lds, acc);
  float* Pz = P + (size_t)kz * 2097152;
#pragma unroll
  for (int i = 0; i < 2; ++i)
#pragma unroll
    for (int j = 0; j < 2; ++j) {
      int R = nt * 128 + wn * 64 + 32 * j + ar;
      int b = R >> 6, d = R & 63;
#pragma unroll
      for (int r = 0; r < 16; ++r) {
        int node = mt * 128 + wm * 64 + 32 * i + crow32(r, hb);
        Pz[((size_t)b * 512 + node) * 64 + d] = acc[i][j][r];
      }
    }
}

// finish cand: c~ = tanh(sum P + G0c + bc); h = u*h + (1-u)*c~
__global__ __launch_bounds__(256) void ru2f_k(const float* __restrict__ P,
                                              const float* __restrict__ G0c,
                                              const float* __restrict__ bc,
                                              const float* __restrict__ U,
                                              float* __restrict__ hT) {
  int i4 = blockIdx.x * 256 + threadIdx.x;
  if (i4 >= 524288) return;
  int base = i4 * 4;
  int d = base & 63;
  f4v_t p0 = *(const f4v_t*)(P + base);
  f4v_t p1 = *(const f4v_t*)(P + 2097152 + base);
  f4v_t p2 = *(const f4v_t*)(P + 2 * 2097152 + base);
  f4v_t p3 = *(const f4v_t*)(P + 3 * 2097152 + base);
  f4v_t g0 = *(const f4v_t*)(G0c + base);
  f4v_t uv = *(const f4v_t*)(U + base);
  f4v_t hv = *(const f4v_t*)(hT + base);
#pragma unroll
  for (int e = 0; e < 4; ++e) {
    float ct = tanhf(p0[e] + p1[e] + p2[e] + p3[e] + g0[e] + bc[d + e]);
    hv[e] = uv[e] * hv[e] + (1.f - uv[e]) * ct;
  }
  *(f4v_t*)(hT + base) = hv;
}

__global__ __launch_bounds__(256) void proj_out_k(const float* __restrict__ h1T,
                                                  const float* __restrict__ pw,
                                                  const float* __restrict__ pb,
                                                  float* __restrict__ ybuf,
                                                  float* __restrict__ out, int k) {
  int idx = blockIdx.x * blockDim.x + threadIdx.x;
  if (idx >= B_ * N_) return;
  float s = pb[0];
  const float* hrow = h1T + (size_t)idx * 64;
#pragma unroll
  for (int j = 0; j < 64; ++j)
    s = fmaf(pw[j], hrow[j], s);
  ybuf[idx] = s;
  out[(size_t)idx * 12 + k] = s;
}

extern "C" void kernel_launch(void* const* d_in, const int* in_sizes, int n_in,
                              void* d_out, int out_size, void* d_ws, size_t ws_size,
                              hipStream_t stream) {
  const float* inputs   = (const float*)d_in[0];
  const float* supports = (const float*)d_in[1];
  const float* Wg[4] = { (const float*)d_in[2],  (const float*)d_in[6],
                         (const float*)d_in[10], (const float*)d_in[14] };
  const float* Bg[4] = { (const float*)d_in[3],  (const float*)d_in[7],
                         (const float*)d_in[11], (const float*)d_in[15] };
  const float* Wc[4] = { (const float*)d_in[4],  (const float*)d_in[8],
                         (const float*)d_in[12], (const float*)d_in[16] };
  const float* Bc[4] = { (const float*)d_in[5],  (const float*)d_in[9],
                         (const float*)d_in[13], (const float*)d_in[17] };
  const float* proj_w = (const float*)d_in[18];
  const float* proj_b = (const float*)d_in[19];
  float* out = (float*)d_out;

  char* p = (char*)d_ws;
  auto carve = [&](size_t bytes) { void* q = p; p += (bytes + 255) & ~(size_t)255; return q; };
  ushort* Bch = (ushort*)carve((size_t)512 * 2048 * 2);
  ushort* zTh = (ushort*)carve((size_t)32768 * 128 * 2);
  ushort* zTl = (ushort*)carve((size_t)32768 * 128 * 2);
  ushort* Gh  = (ushort*)carve((size_t)8192 * 2048 * 2);
  float*  G0T = (float*)carve((size_t)32768 * 128 * 4);
  float*  P   = (float*)carve((size_t)3 * 4194304 * 4);   // 48MB: ru1 3x / ru2 4x(2M) partials
  float*  U   = (float*)carve((size_t)2097152 * 4);
  float*  h0  = (float*)carve((size_t)2097152 * 4);
  float*  h1  = (float*)carve((size_t)2097152 * 4);
  float*  ybuf = (float*)carve((size_t)B_ * N_ * 4);
  ushort* Wgh[4]; ushort* Wgl[4]; ushort* Wch[4]; ushort* Wcl[4];
  for (int c = 0; c < 4; ++c) {
    Wgh[c] = (ushort*)carve((size_t)640 * 128 * 2);
    Wgl[c] = (ushort*)carve((size_t)640 * 128 * 2);
    Wch[c] = (ushort*)carve((size_t)384 * 128 * 2);
    Wcl[c] = (ushort*)carve((size_t)384 * 128 * 2);
  }
  float* SSbuf = (float*)U;      // SS only needed during prep

  hipMemsetAsync(h0, 0, (size_t)2097152 * 4, stream);
  hipMemsetAsync(h1, 0, (size_t)2097152 * 4, stream);
  hipMemsetAsync(ybuf, 0, (size_t)B_ * N_ * 4, stream);

  ssq_k<<<dim3(32, 32, 2), dim3(16, 16), 0, stream>>>(supports, SSbuf);
  bcat_k<<<(512 * 2048 + 255) / 256, 256, 0, stream>>>(supports, SSbuf, Bch);
  const int Cs[4] = { 66, 128, 65, 128 };
  for (int c = 0; c < 4; ++c) {
    wprep2_k<<<(640 * 128 + 255) / 256, 256, 0, stream>>>(Wg[c], Wgh[c], Wgl[c], Cs[c], 128, 640);
    wprep2_k<<<(384 * 128 + 255) / 256, 256, 0, stream>>>(Wc[c], Wch[c], Wcl[c], Cs[c], 64, 384);
  }

  auto cell = [&](int ci, int Cx, const float* x, int xmode, int t, float* h) {
    int C = Cx + 64;
    int K1 = (C + 31) & ~31;   // 96 or 128
    packzT_k<<<128, 256, 0, stream>>>(x, xmode, t, Cx, C, h, zTh, zTl);
    g1_k<0><<<dim3(256, 5), 256, 0, stream>>>(Wgh[ci], Wgl[ci], zTh, zTl, Gh, G0T, K1, 640);
    ru1g_k<<<dim3(64, 4, 3), 256, 0, stream>>>(Gh, Bch, P);
    ru1f_k<<<4096, 256, 0, stream>>>(P, G0T, Bg[ci], h, U, zTh, zTl, Cx);
    g1_k<1><<<dim3(256, 3), 256, 0, stream>>>(Wch[ci], Wcl[ci], zTh, zTl, Gh, G0T, K1, 320);
    ru2g_k<<<dim3(32, 4, 4), 256, 0, stream>>>(Gh, Bch, P);
    ru2f_k<<<2048, 256, 0, stream>>>(P, G0T, Bc[ci], U, h);
  };

  for (int t = 0; t < 12; ++t) {
    cell(0, 2, inputs, 0, t, h0);
    cell(1, 64, h0, 2, 0, h1);
  }
  for (int k = 0; k < 12; ++k) {
    cell(2, 1, ybuf, 1, 0, h0);
    cell(3, 64, h0, 2, 0, h1);
    proj_out_k<<<(B_ * N_ + 255) / 256, 256, 0, stream>>>(h1, proj_w, proj_b, ybuf, out, k);
  }
}

// Round 12
// 6449.558 us; speedup vs baseline: 2.3153x; 1.1924x over previous
//
#include <hip/hip_runtime.h>

#define B_ 64
#define N_ 512

typedef __attribute__((ext_vector_type(8))) short bf8_t;    // 8 bf16 (4 VGPRs)
typedef __attribute__((ext_vector_type(16))) float f16_t;   // 32x32 MFMA acc
typedef __attribute__((ext_vector_type(4))) float f4v_t;

#define MFMA32(a, b, c) __builtin_amdgcn_mfma_f32_32x32x16_bf16(a, b, c, 0, 0, 0)

__device__ __forceinline__ ushort f2bf(float x) {
  union { float f; unsigned u; } v; v.f = x;
  unsigned r = v.u + 0x7FFFu + ((v.u >> 16) & 1u);   // RNE
  return (ushort)(r >> 16);
}
__device__ __forceinline__ float bf2f(ushort h) {
  union { unsigned u; float f; } v; v.u = ((unsigned)h) << 16;
  return v.f;
}

__device__ __forceinline__ void gld16(const ushort* g, ushort* l) {
  __builtin_amdgcn_global_load_lds(
      (const __attribute__((address_space(1))) unsigned int*)(uintptr_t)g,
      (__attribute__((address_space(3))) unsigned int*)(uintptr_t)l,
      16, 0, 0);
}

// XCD-aware bijective swizzle
__device__ __forceinline__ int xcd_logical(int nwg) {
  int lin = blockIdx.x + gridDim.x * (blockIdx.y + gridDim.y * blockIdx.z);
  return (lin & 7) * (nwg >> 3) + (lin >> 3);
}

// XOR swizzle (BK=32: 4x 16B slots/row; (r>>1)&3 spread → 2-way = free)
__device__ __forceinline__ int swz32(int r) { return (r >> 1) & 3; }

template <int ROWS, int THREADS>
__device__ __forceinline__ void stage_tile2(const ushort* g, int lda, int k0,
                                            ushort* l, int tid) {
  constexpr int RT = (ROWS * 32) / (THREADS * 8);
#pragma unroll
  for (int q = 0; q < RT; ++q) {
    int e  = q * THREADS * 8 + tid * 8;
    int r  = e >> 5;
    int c8 = (e >> 3) & 3;
    int g8 = c8 ^ swz32(r);
    gld16(g + (size_t)r * lda + k0 + g8 * 8, l + e);
  }
}

// ---------------------------------------------------------------------------
// 4-tile split-bf16 core (3-term): used by g1id (identity rows, f32-precision).
// ---------------------------------------------------------------------------
__device__ __forceinline__ void core128(
    const ushort* Ah, const ushort* Al, int lda,
    const ushort* Bh, const ushort* Bl, int ldb,
    int K, ushort* lds, f16_t acc[2][2]) {
  constexpr int TILE = 128 * 32;
  constexpr int SSZ  = 4 * TILE;
  const int tid = threadIdx.x, lane = tid & 63, wave = tid >> 6;
  const int ar = lane & 31, hb = lane >> 5;
  const int wm = wave >> 1, wn = wave & 1;

  auto stage = [&](int buf, int k0) {
    ushort* lb = lds + buf * SSZ;
    stage_tile2<128, 256>(Ah, lda, k0, lb, tid);
    stage_tile2<128, 256>(Al, lda, k0, lb + TILE, tid);
    stage_tile2<128, 256>(Bh, ldb, k0, lb + 2 * TILE, tid);
    stage_tile2<128, 256>(Bl, ldb, k0, lb + 3 * TILE, tid);
  };

  const int nc = K >> 5;
  stage(0, 0);
  int buf = 0;
  for (int c = 0; c < nc; ++c) {
    __syncthreads();
    if (c + 1 < nc) stage(buf ^ 1, (c + 1) << 5);
    const ushort* lb = lds + buf * SSZ;
#pragma unroll
    for (int ks = 0; ks < 2; ++ks) {
      bf8_t ah[2], al[2], bh[2], bl[2];
#pragma unroll
      for (int i = 0; i < 2; ++i) {
        int r = wm * 64 + 32 * i + ar;
        int c8 = (ks * 2 + hb) ^ swz32(r);
        ah[i] = *(const bf8_t*)(lb + r * 32 + c8 * 8);
        al[i] = *(const bf8_t*)(lb + TILE + r * 32 + c8 * 8);
      }
#pragma unroll
      for (int j = 0; j < 2; ++j) {
        int r = wn * 64 + 32 * j + ar;
        int c8 = (ks * 2 + hb) ^ swz32(r);
        bh[j] = *(const bf8_t*)(lb + 2 * TILE + r * 32 + c8 * 8);
        bl[j] = *(const bf8_t*)(lb + 3 * TILE + r * 32 + c8 * 8);
      }
#pragma unroll
      for (int i = 0; i < 2; ++i)
#pragma unroll
        for (int j = 0; j < 2; ++j) {
          acc[i][j] = MFMA32(ah[i], bh[j], acc[i][j]);
          acc[i][j] = MFMA32(ah[i], bl[j], acc[i][j]);
          acc[i][j] = MFMA32(al[i], bh[j], acc[i][j]);
        }
    }
    buf ^= 1;
  }
}

// ---------------------------------------------------------------------------
// 2-tile core (1-term pure bf16). 32KB LDS dbuf. Used by g1diff / ru1g / ru2g.
// Outputs that are bf16-stored or diffusion-averaged tolerate 1-term error.
// ---------------------------------------------------------------------------
__device__ __forceinline__ void core128_1(
    const ushort* Ah, int lda,
    const ushort* Bh, int ldb,
    int K, ushort* lds, f16_t acc[2][2]) {
  constexpr int TILE = 128 * 32;
  constexpr int SSZ  = 2 * TILE;
  const int tid = threadIdx.x, lane = tid & 63, wave = tid >> 6;
  const int ar = lane & 31, hb = lane >> 5;
  const int wm = wave >> 1, wn = wave & 1;

  auto stage = [&](int buf, int k0) {
    ushort* lb = lds + buf * SSZ;
    stage_tile2<128, 256>(Ah, lda, k0, lb, tid);
    stage_tile2<128, 256>(Bh, ldb, k0, lb + TILE, tid);
  };

  const int nc = K >> 5;
  stage(0, 0);
  int buf = 0;
  for (int c = 0; c < nc; ++c) {
    __syncthreads();
    if (c + 1 < nc) stage(buf ^ 1, (c + 1) << 5);
    const ushort* lb = lds + buf * SSZ;
#pragma unroll
    for (int ks = 0; ks < 2; ++ks) {
      bf8_t ah[2], bh[2];
#pragma unroll
      for (int i = 0; i < 2; ++i) {
        int r = wm * 64 + 32 * i + ar;
        int c8 = (ks * 2 + hb) ^ swz32(r);
        ah[i] = *(const bf8_t*)(lb + r * 32 + c8 * 8);
      }
#pragma unroll
      for (int j = 0; j < 2; ++j) {
        int r = wn * 64 + 32 * j + ar;
        int c8 = (ks * 2 + hb) ^ swz32(r);
        bh[j] = *(const bf8_t*)(lb + TILE + r * 32 + c8 * 8);
      }
#pragma unroll
      for (int i = 0; i < 2; ++i)
#pragma unroll
        for (int j = 0; j < 2; ++j)
          acc[i][j] = MFMA32(ah[i], bh[j], acc[i][j]);
    }
    buf ^= 1;
  }
}

// C/D row-within-frag for 32x32: (r&3) + 8*(r>>2) + 4*hb
__device__ __forceinline__ int crow32(int r, int hb) {
  return (r & 3) + 8 * (r >> 2) + 4 * hb;
}

// ---------------------------------------------------------------------------
// Prep
// ---------------------------------------------------------------------------
__global__ __launch_bounds__(256) void ssq_k(const float* __restrict__ S,
                                             float* __restrict__ SS) {
  int s = blockIdx.z;
  const float* Ss = S + s * N_ * N_;
  __shared__ float Ta[16][17], Tb[16][17];
  int n = blockIdx.y * 16 + threadIdx.y;
  int m = blockIdx.x * 16 + threadIdx.x;
  float acc = 0.f;
  for (int p0 = 0; p0 < N_; p0 += 16) {
    Ta[threadIdx.y][threadIdx.x] = Ss[n * N_ + p0 + threadIdx.x];
    Tb[threadIdx.y][threadIdx.x] = Ss[(p0 + threadIdx.y) * N_ + m];
    __syncthreads();
#pragma unroll
    for (int pp = 0; pp < 16; ++pp)
      acc = fmaf(Ta[threadIdx.y][pp], Tb[pp][threadIdx.x], acc);
    __syncthreads();
  }
  SS[((size_t)s * N_ + n) * N_ + m] = acc;
}

// Bcat[n][k] hi only, k = seg*512+m, segs [S0, S0^2, S1, S1^2]
__global__ __launch_bounds__(256) void bcat_k(const float* __restrict__ S,
                                              const float* __restrict__ SS,
                                              ushort* __restrict__ Bh) {
  int idx = blockIdx.x * 256 + threadIdx.x;
  if (idx >= 512 * 2048) return;
  int k = idx & 2047, n = idx >> 11;
  int seg = k >> 9, m = k & 511;
  float v;
  if (seg == 0)      v = S[(size_t)n * 512 + m];
  else if (seg == 1) v = SS[(size_t)n * 512 + m];
  else if (seg == 2) v = S[(size_t)(512 + n) * 512 + m];
  else               v = SS[(size_t)(512 + n) * 512 + m];
  Bh[idx] = f2bf(v);
}

// identity-block weights: Wt_id[d][c] hi/lo, from W[(0*C+c)*Dout + d]
__global__ __launch_bounds__(256) void wprep_id_k(const float* __restrict__ W,
                                                  ushort* __restrict__ Wh,
                                                  ushort* __restrict__ Wl,
                                                  int C, int Dout) {
  int idx = blockIdx.x * 256 + threadIdx.x;
  if (idx >= Dout * 128) return;
  int c = idx & 127, d = idx >> 7;
  float v = (c < C) ? W[(size_t)c * Dout + d] : 0.f;
  ushort hh = f2bf(v);
  Wh[idx] = hh; Wl[idx] = f2bf(v - bf2f(hh));
}

// diffusion-block weights: Wd[i = (t-1)*Dout + d][c] hi only, t=1..4
__global__ __launch_bounds__(256) void wprep_diff_k(const float* __restrict__ W,
                                                    ushort* __restrict__ Wh,
                                                    int C, int Dout) {
  int idx = blockIdx.x * 256 + threadIdx.x;
  if (idx >= 4 * Dout * 128) return;
  int c = idx & 127, i = idx >> 7;
  int t = 1 + i / Dout, d = i % Dout;
  float v = (c < C) ? W[(size_t)(t * C + c) * Dout + d] : 0.f;
  Wh[idx] = f2bf(v);
}

// ---------------------------------------------------------------------------
// Pack zT[(b,n)][c] = [x | h | 0-pad], split hi/lo. hT is [(b,n)][d].
// xmode 0: inputs gather (t); xmode 1: flat [jg]; xmode 2: hT-row layout
// ---------------------------------------------------------------------------
__global__ __launch_bounds__(256) void packzT_k(const float* __restrict__ xsrc,
                                                int xmode, int t, int Cx, int C,
                                                const float* __restrict__ hT,
                                                ushort* __restrict__ Zh,
                                                ushort* __restrict__ Zl) {
  int jg = blockIdx.x * 256 + threadIdx.x;   // b*512 + n
  int b = jg >> 9, n = jg & 511;
  for (int c0 = 0; c0 < 128; c0 += 8) {
    bf8_t vh, vl;
#pragma unroll
    for (int q = 0; q < 8; ++q) {
      int c = c0 + q;
      float v;
      if (c < Cx) {
        if (xmode == 0)      v = xsrc[((size_t)(b * Cx + c) * 512 + n) * 12 + t];
        else if (xmode == 1) v = xsrc[jg];
        else                 v = xsrc[(size_t)jg * 64 + c];
      } else if (c < C) {
        v = hT[(size_t)jg * 64 + (c - Cx)];
      } else {
        v = 0.f;
      }
      ushort hh = f2bf(v);
      vh[q] = (short)hh;
      vl[q] = (short)f2bf(v - bf2f(hh));
    }
    *(bf8_t*)(Zh + (size_t)jg * 128 + c0) = vh;
    *(bf8_t*)(Zl + (size_t)jg * 128 + c0) = vl;
  }
}

// ---------------------------------------------------------------------------
// g1 identity rows (3-term): G0T[jg*DR + d] = W0^T z. M = DR (128 gate/64 cand)
// grid (256 nt). K = K1.
// ---------------------------------------------------------------------------
template <int MODE>
__global__ __launch_bounds__(256, 2) void g1id_k(const ushort* __restrict__ Wh,
                                                 const ushort* __restrict__ Wl,
                                                 const ushort* __restrict__ Zh,
                                                 const ushort* __restrict__ Zl,
                                                 float* __restrict__ G0T, int K) {
  __shared__ __attribute__((aligned(16))) ushort lds[2 * 4 * 128 * 32];
  constexpr int DR = (MODE == 0) ? 128 : 64;
  int tid = threadIdx.x, lane = tid & 63, wave = tid >> 6;
  int wm = wave >> 1, wn = wave & 1, ar = lane & 31, hb = lane >> 5;
  int nt = xcd_logical(256);
  f16_t acc[2][2] = {};
  core128(Wh, Wl, 128,
          Zh + (size_t)nt * 128 * 128, Zl + (size_t)nt * 128 * 128, 128,
          K, lds, acc);
#pragma unroll
  for (int i = 0; i < 2; ++i)
#pragma unroll
    for (int j = 0; j < 2; ++j) {
      int jg = nt * 128 + wn * 64 + 32 * j + ar;
#pragma unroll
      for (int r = 0; r < 16; ++r) {
        int d = wm * 64 + 32 * i + crow32(r, hb);
        if (d >= DR) continue;
        G0T[(size_t)jg * DR + d] = acc[i][j][r];
      }
    }
}

// ---------------------------------------------------------------------------
// g1 diffusion rows (1-term): Gh[(b*DR+d)*2048 + tt*512 + m] = W_{tt+1}^T z.
// M = 4*DR (512 gate / 256 cand), grid (256 nt, NMT mt), NMT = 4 / 2.
// ---------------------------------------------------------------------------
template <int MODE>
__global__ __launch_bounds__(256, 3) void g1diff_k(const ushort* __restrict__ Wd,
                                                   const ushort* __restrict__ Zh,
                                                   ushort* __restrict__ Gh, int K) {
  __shared__ __attribute__((aligned(16))) ushort lds[2 * 2 * 128 * 32];
  constexpr int DR = (MODE == 0) ? 128 : 64;
  constexpr int NMT = (MODE == 0) ? 4 : 2;
  int tid = threadIdx.x, lane = tid & 63, wave = tid >> 6;
  int wm = wave >> 1, wn = wave & 1, ar = lane & 31, hb = lane >> 5;
  int L = xcd_logical(256 * NMT);
  int mt = L % NMT, nt = L / NMT;
  f16_t acc[2][2] = {};
  core128_1(Wd + (size_t)mt * 128 * 128, 128,
            Zh + (size_t)nt * 128 * 128, 128,
            K, lds, acc);
#pragma unroll
  for (int i = 0; i < 2; ++i)
#pragma unroll
    for (int j = 0; j < 2; ++j) {
      int jg = nt * 128 + wn * 64 + 32 * j + ar;
      int b = jg >> 9, m = jg & 511;
#pragma unroll
      for (int r = 0; r < 16; ++r) {
        int ii = mt * 128 + wm * 64 + 32 * i + crow32(r, hb);
        int tt = ii / DR, d = ii % DR;
        Gh[((size_t)(b * DR + d)) * 2048 + (size_t)tt * 512 + m] = f2bf(acc[i][j][r]);
      }
    }
}

// ---------------------------------------------------------------------------
// Gate diffusion GEMM (1-term, 2-tile), split-K kz=3 (768/768/512): -> P
// ---------------------------------------------------------------------------
__global__ __launch_bounds__(256, 3) void ru1g_k(const ushort* __restrict__ Gh,
                                                 const ushort* __restrict__ Bch,
                                                 float* __restrict__ P) {
  __shared__ __attribute__((aligned(16))) ushort lds[2 * 2 * 128 * 32];
  int tid = threadIdx.x, lane = tid & 63, wave = tid >> 6;
  int wm = wave >> 1, wn = wave & 1, ar = lane & 31, hb = lane >> 5;
  int L = xcd_logical(768);
  int mt = L & 3, nt = (L >> 2) & 63, kz = L >> 8;   // kz 0..2
  int k0 = kz * 768;
  int K  = (kz == 2) ? 512 : 768;
  f16_t acc[2][2] = {};
  core128_1(Bch + (size_t)mt * 128 * 2048 + k0, 2048,
            Gh + (size_t)nt * 128 * 2048 + k0, 2048,
            K, lds, acc);
  float* Pz = P + (size_t)kz * 4194304;
#pragma unroll
  for (int i = 0; i < 2; ++i)
#pragma unroll
    for (int j = 0; j < 2; ++j) {
      int R = nt * 128 + wn * 64 + 32 * j + ar;
      int b = R >> 7, d = R & 127;
#pragma unroll
      for (int r = 0; r < 16; ++r) {
        int node = mt * 128 + wm * 64 + 32 * i + crow32(r, hb);
        Pz[((size_t)b * 512 + node) * 128 + d] = acc[i][j][r];
      }
    }
}

// finish gate: sigmoid(P0+P1+P2+G0T+bg); d<64 -> r*h into zT; d>=64 -> u into U
__global__ __launch_bounds__(256) void ru1f_k(const float* __restrict__ P,
                                              const float* __restrict__ G0T,
                                              const float* __restrict__ bg,
                                              const float* __restrict__ hT,
                                              float* __restrict__ U,
                                              ushort* __restrict__ Zh,
                                              ushort* __restrict__ Zl, int Cx) {
  int i4 = blockIdx.x * 256 + threadIdx.x;
  if (i4 >= 1048576) return;
  int base = i4 * 4;
  int row = base >> 7, d = base & 127;
  f4v_t p0 = *(const f4v_t*)(P + base);
  f4v_t p1 = *(const f4v_t*)(P + 4194304 + base);
  f4v_t p2 = *(const f4v_t*)(P + 2 * 4194304 + base);
  f4v_t g0 = *(const f4v_t*)(G0T + base);
  if (d < 64) {
    f4v_t hv = *(const f4v_t*)(hT + (size_t)row * 64 + d);
#pragma unroll
    for (int e = 0; e < 4; ++e) {
      float s = 1.f / (1.f + expf(-(p0[e] + p1[e] + p2[e] + g0[e] + bg[d + e])));
      float rh = s * hv[e];
      ushort hh = f2bf(rh);
      Zh[(size_t)row * 128 + Cx + d + e] = hh;
      Zl[(size_t)row * 128 + Cx + d + e] = f2bf(rh - bf2f(hh));
    }
  } else {
    f4v_t uo;
#pragma unroll
    for (int e = 0; e < 4; ++e)
      uo[e] = 1.f / (1.f + expf(-(p0[e] + p1[e] + p2[e] + g0[e] + bg[d + e])));
    *(f4v_t*)(U + (size_t)row * 64 + (d - 64)) = uo;
  }
}

// ---------------------------------------------------------------------------
// Cand diffusion GEMM (1-term, 2-tile), split-K kz=4.
// ---------------------------------------------------------------------------
__global__ __launch_bounds__(256, 3) void ru2g_k(const ushort* __restrict__ Gh,
                                                 const ushort* __restrict__ Bch,
                                                 float* __restrict__ P) {
  __shared__ __attribute__((aligned(16))) ushort lds[2 * 2 * 128 * 32];
  int tid = threadIdx.x, lane = tid & 63, wave = tid >> 6;
  int wm = wave >> 1, wn = wave & 1, ar = lane & 31, hb = lane >> 5;
  int L = xcd_logical(512);
  int mt = L & 3, nt = (L >> 2) & 31, kz = L >> 7;
  f16_t acc[2][2] = {};
  core128_1(Bch + (size_t)mt * 128 * 2048 + kz * 512, 2048,
            Gh + (size_t)nt * 128 * 2048 + kz * 512, 2048,
            512, lds, acc);
  float* Pz = P + (size_t)kz * 2097152;
#pragma unroll
  for (int i = 0; i < 2; ++i)
#pragma unroll
    for (int j = 0; j < 2; ++j) {
      int R = nt * 128 + wn * 64 + 32 * j + ar;
      int b = R >> 6, d = R & 63;
#pragma unroll
      for (int r = 0; r < 16; ++r) {
        int node = mt * 128 + wm * 64 + 32 * i + crow32(r, hb);
        Pz[((size_t)b * 512 + node) * 64 + d] = acc[i][j][r];
      }
    }
}

// finish cand: c~ = tanh(sum P + G0c + bc); h = u*h + (1-u)*c~
__global__ __launch_bounds__(256) void ru2f_k(const float* __restrict__ P,
                                              const float* __restrict__ G0c,
                                              const float* __restrict__ bc,
                                              const float* __restrict__ U,
                                              float* __restrict__ hT) {
  int i4 = blockIdx.x * 256 + threadIdx.x;
  if (i4 >= 524288) return;
  int base = i4 * 4;
  int d = base & 63;
  f4v_t p0 = *(const f4v_t*)(P + base);
  f4v_t p1 = *(const f4v_t*)(P + 2097152 + base);
  f4v_t p2 = *(const f4v_t*)(P + 2 * 2097152 + base);
  f4v_t p3 = *(const f4v_t*)(P + 3 * 2097152 + base);
  f4v_t g0 = *(const f4v_t*)(G0c + base);
  f4v_t uv = *(const f4v_t*)(U + base);
  f4v_t hv = *(const f4v_t*)(hT + base);
#pragma unroll
  for (int e = 0; e < 4; ++e) {
    float ct = tanhf(p0[e] + p1[e] + p2[e] + p3[e] + g0[e] + bc[d + e]);
    hv[e] = uv[e] * hv[e] + (1.f - uv[e]) * ct;
  }
  *(f4v_t*)(hT + base) = hv;
}

__global__ __launch_bounds__(256) void proj_out_k(const float* __restrict__ h1T,
                                                  const float* __restrict__ pw,
                                                  const float* __restrict__ pb,
                                                  float* __restrict__ ybuf,
                                                  float* __restrict__ out, int k) {
  int idx = blockIdx.x * blockDim.x + threadIdx.x;
  if (idx >= B_ * N_) return;
  float s = pb[0];
  const float* hrow = h1T + (size_t)idx * 64;
#pragma unroll
  for (int j = 0; j < 64; ++j)
    s = fmaf(pw[j], hrow[j], s);
  ybuf[idx] = s;
  out[(size_t)idx * 12 + k] = s;
}

extern "C" void kernel_launch(void* const* d_in, const int* in_sizes, int n_in,
                              void* d_out, int out_size, void* d_ws, size_t ws_size,
                              hipStream_t stream) {
  const float* inputs   = (const float*)d_in[0];
  const float* supports = (const float*)d_in[1];
  const float* Wg[4] = { (const float*)d_in[2],  (const float*)d_in[6],
                         (const float*)d_in[10], (const float*)d_in[14] };
  const float* Bg[4] = { (const float*)d_in[3],  (const float*)d_in[7],
                         (const float*)d_in[11], (const float*)d_in[15] };
  const float* Wc[4] = { (const float*)d_in[4],  (const float*)d_in[8],
                         (const float*)d_in[12], (const float*)d_in[16] };
  const float* Bc[4] = { (const float*)d_in[5],  (const float*)d_in[9],
                         (const float*)d_in[13], (const float*)d_in[17] };
  const float* proj_w = (const float*)d_in[18];
  const float* proj_b = (const float*)d_in[19];
  float* out = (float*)d_out;

  char* p = (char*)d_ws;
  auto carve = [&](size_t bytes) { void* q = p; p += (bytes + 255) & ~(size_t)255; return q; };
  ushort* Bch = (ushort*)carve((size_t)512 * 2048 * 2);
  ushort* zTh = (ushort*)carve((size_t)32768 * 128 * 2);
  ushort* zTl = (ushort*)carve((size_t)32768 * 128 * 2);
  ushort* Gh  = (ushort*)carve((size_t)8192 * 2048 * 2);
  float*  G0T = (float*)carve((size_t)32768 * 128 * 4);
  float*  P   = (float*)carve((size_t)3 * 4194304 * 4);   // 48MB partials
  float*  U   = (float*)carve((size_t)2097152 * 4);
  float*  h0  = (float*)carve((size_t)2097152 * 4);
  float*  h1  = (float*)carve((size_t)2097152 * 4);
  float*  ybuf = (float*)carve((size_t)B_ * N_ * 4);
  // per cell-type: id weights (hi/lo) + diff weights (hi only)
  ushort* Wgid_h[4]; ushort* Wgid_l[4]; ushort* Wgd[4];
  ushort* Wcid_h[4]; ushort* Wcid_l[4]; ushort* Wcd[4];
  for (int c = 0; c < 4; ++c) {
    Wgid_h[c] = (ushort*)carve((size_t)128 * 128 * 2);
    Wgid_l[c] = (ushort*)carve((size_t)128 * 128 * 2);
    Wgd[c]    = (ushort*)carve((size_t)512 * 128 * 2);
    Wcid_h[c] = (ushort*)carve((size_t)64 * 128 * 2);
    Wcid_l[c] = (ushort*)carve((size_t)64 * 128 * 2);
    Wcd[c]    = (ushort*)carve((size_t)256 * 128 * 2);
  }
  float* SSbuf = (float*)U;      // SS only needed during prep

  hipMemsetAsync(h0, 0, (size_t)2097152 * 4, stream);
  hipMemsetAsync(h1, 0, (size_t)2097152 * 4, stream);
  hipMemsetAsync(ybuf, 0, (size_t)B_ * N_ * 4, stream);

  ssq_k<<<dim3(32, 32, 2), dim3(16, 16), 0, stream>>>(supports, SSbuf);
  bcat_k<<<(512 * 2048 + 255) / 256, 256, 0, stream>>>(supports, SSbuf, Bch);
  const int Cs[4] = { 66, 128, 65, 128 };
  for (int c = 0; c < 4; ++c) {
    wprep_id_k<<<(128 * 128 + 255) / 256, 256, 0, stream>>>(Wg[c], Wgid_h[c], Wgid_l[c], Cs[c], 128);
    wprep_diff_k<<<(4 * 128 * 128 + 255) / 256, 256, 0, stream>>>(Wg[c], Wgd[c], Cs[c], 128);
    wprep_id_k<<<(64 * 128 + 255) / 256, 256, 0, stream>>>(Wc[c], Wcid_h[c], Wcid_l[c], Cs[c], 64);
    wprep_diff_k<<<(4 * 64 * 128 + 255) / 256, 256, 0, stream>>>(Wc[c], Wcd[c], Cs[c], 64);
  }

  auto cell = [&](int ci, int Cx, const float* x, int xmode, int t, float* h) {
    int C = Cx + 64;
    int K1 = (C + 31) & ~31;   // 96 or 128
    packzT_k<<<128, 256, 0, stream>>>(x, xmode, t, Cx, C, h, zTh, zTl);
    g1id_k<0><<<256, 256, 0, stream>>>(Wgid_h[ci], Wgid_l[ci], zTh, zTl, G0T, K1);
    g1diff_k<0><<<dim3(256, 4), 256, 0, stream>>>(Wgd[ci], zTh, Gh, K1);
    ru1g_k<<<dim3(64, 4, 3), 256, 0, stream>>>(Gh, Bch, P);
    ru1f_k<<<4096, 256, 0, stream>>>(P, G0T, Bg[ci], h, U, zTh, zTl, Cx);
    g1id_k<1><<<256, 256, 0, stream>>>(Wcid_h[ci], Wcid_l[ci], zTh, zTl, G0T, K1);
    g1diff_k<1><<<dim3(256, 2), 256, 0, stream>>>(Wcd[ci], zTh, Gh, K1);
    ru2g_k<<<dim3(32, 4, 4), 256, 0, stream>>>(Gh, Bch, P);
    ru2f_k<<<2048, 256, 0, stream>>>(P, G0T, Bc[ci], U, h);
  };

  for (int t = 0; t < 12; ++t) {
    cell(0, 2, inputs, 0, t, h0);
    cell(1, 64, h0, 2, 0, h1);
  }
  for (int k = 0; k < 12; ++k) {
    cell(2, 1, ybuf, 1, 0, h0);
    cell(3, 64, h0, 2, 0, h1);
    proj_out_k<<<(B_ * N_ + 255) / 256, 256, 0, stream>>>(h1, proj_w, proj_b, ybuf, out, k);
  }
}

// Round 13
// 6206.272 us; speedup vs baseline: 2.4061x; 1.0392x over previous
//
#include <hip/hip_runtime.h>

#define B_ 64
#define N_ 512

typedef __attribute__((ext_vector_type(8))) short bf8_t;    // 8 bf16 (4 VGPRs)
typedef __attribute__((ext_vector_type(16))) float f16_t;   // 32x32 MFMA acc
typedef __attribute__((ext_vector_type(4))) float f4v_t;

#define MFMA32(a, b, c) __builtin_amdgcn_mfma_f32_32x32x16_bf16(a, b, c, 0, 0, 0)

__device__ __forceinline__ ushort f2bf(float x) {
  union { float f; unsigned u; } v; v.f = x;
  unsigned r = v.u + 0x7FFFu + ((v.u >> 16) & 1u);   // RNE
  return (ushort)(r >> 16);
}
__device__ __forceinline__ float bf2f(ushort h) {
  union { unsigned u; float f; } v; v.u = ((unsigned)h) << 16;
  return v.f;
}

__device__ __forceinline__ void gld16(const ushort* g, ushort* l) {
  __builtin_amdgcn_global_load_lds(
      (const __attribute__((address_space(1))) unsigned int*)(uintptr_t)g,
      (__attribute__((address_space(3))) unsigned int*)(uintptr_t)l,
      16, 0, 0);
}

// XCD-aware bijective swizzle (nwg must be divisible by 8)
__device__ __forceinline__ int xcd_logical(int nwg) {
  int lin = blockIdx.x + gridDim.x * (blockIdx.y + gridDim.y * blockIdx.z);
  return (lin & 7) * (nwg >> 3) + (lin >> 3);
}

// XOR swizzle (BK=32: 4x 16B slots/row; (r>>1)&3 spread → 2-way = free)
__device__ __forceinline__ int swz32(int r) { return (r >> 1) & 3; }

template <int ROWS, int THREADS>
__device__ __forceinline__ void stage_tile2(const ushort* g, int lda, int k0,
                                            ushort* l, int tid) {
  constexpr int RT = (ROWS * 32) / (THREADS * 8);
#pragma unroll
  for (int q = 0; q < RT; ++q) {
    int e  = q * THREADS * 8 + tid * 8;
    int r  = e >> 5;
    int c8 = (e >> 3) & 3;
    int g8 = c8 ^ swz32(r);
    gld16(g + (size_t)r * lda + k0 + g8 * 8, l + e);
  }
}

// ---------------------------------------------------------------------------
// 4-tile split-bf16 core (3-term): identity rows (f32-precision results).
// ---------------------------------------------------------------------------
__device__ __forceinline__ void core128(
    const ushort* Ah, const ushort* Al, int lda,
    const ushort* Bh, const ushort* Bl, int ldb,
    int K, ushort* lds, f16_t acc[2][2]) {
  constexpr int TILE = 128 * 32;
  constexpr int SSZ  = 4 * TILE;
  const int tid = threadIdx.x, lane = tid & 63, wave = tid >> 6;
  const int ar = lane & 31, hb = lane >> 5;
  const int wm = wave >> 1, wn = wave & 1;

  auto stage = [&](int buf, int k0) {
    ushort* lb = lds + buf * SSZ;
    stage_tile2<128, 256>(Ah, lda, k0, lb, tid);
    stage_tile2<128, 256>(Al, lda, k0, lb + TILE, tid);
    stage_tile2<128, 256>(Bh, ldb, k0, lb + 2 * TILE, tid);
    stage_tile2<128, 256>(Bl, ldb, k0, lb + 3 * TILE, tid);
  };

  const int nc = K >> 5;
  stage(0, 0);
  int buf = 0;
  for (int c = 0; c < nc; ++c) {
    __syncthreads();
    if (c + 1 < nc) stage(buf ^ 1, (c + 1) << 5);
    const ushort* lb = lds + buf * SSZ;
#pragma unroll
    for (int ks = 0; ks < 2; ++ks) {
      bf8_t ah[2], al[2], bh[2], bl[2];
#pragma unroll
      for (int i = 0; i < 2; ++i) {
        int r = wm * 64 + 32 * i + ar;
        int c8 = (ks * 2 + hb) ^ swz32(r);
        ah[i] = *(const bf8_t*)(lb + r * 32 + c8 * 8);
        al[i] = *(const bf8_t*)(lb + TILE + r * 32 + c8 * 8);
      }
#pragma unroll
      for (int j = 0; j < 2; ++j) {
        int r = wn * 64 + 32 * j + ar;
        int c8 = (ks * 2 + hb) ^ swz32(r);
        bh[j] = *(const bf8_t*)(lb + 2 * TILE + r * 32 + c8 * 8);
        bl[j] = *(const bf8_t*)(lb + 3 * TILE + r * 32 + c8 * 8);
      }
#pragma unroll
      for (int i = 0; i < 2; ++i)
#pragma unroll
        for (int j = 0; j < 2; ++j) {
          acc[i][j] = MFMA32(ah[i], bh[j], acc[i][j]);
          acc[i][j] = MFMA32(ah[i], bl[j], acc[i][j]);
          acc[i][j] = MFMA32(al[i], bh[j], acc[i][j]);
        }
    }
    buf ^= 1;
  }
}

// ---------------------------------------------------------------------------
// 2-tile core (1-term pure bf16). 32KB LDS dbuf.
// ---------------------------------------------------------------------------
__device__ __forceinline__ void core128_1(
    const ushort* Ah, int lda,
    const ushort* Bh, int ldb,
    int K, ushort* lds, f16_t acc[2][2]) {
  constexpr int TILE = 128 * 32;
  constexpr int SSZ  = 2 * TILE;
  const int tid = threadIdx.x, lane = tid & 63, wave = tid >> 6;
  const int ar = lane & 31, hb = lane >> 5;
  const int wm = wave >> 1, wn = wave & 1;

  auto stage = [&](int buf, int k0) {
    ushort* lb = lds + buf * SSZ;
    stage_tile2<128, 256>(Ah, lda, k0, lb, tid);
    stage_tile2<128, 256>(Bh, ldb, k0, lb + TILE, tid);
  };

  const int nc = K >> 5;
  stage(0, 0);
  int buf = 0;
  for (int c = 0; c < nc; ++c) {
    __syncthreads();
    if (c + 1 < nc) stage(buf ^ 1, (c + 1) << 5);
    const ushort* lb = lds + buf * SSZ;
#pragma unroll
    for (int ks = 0; ks < 2; ++ks) {
      bf8_t ah[2], bh[2];
#pragma unroll
      for (int i = 0; i < 2; ++i) {
        int r = wm * 64 + 32 * i + ar;
        int c8 = (ks * 2 + hb) ^ swz32(r);
        ah[i] = *(const bf8_t*)(lb + r * 32 + c8 * 8);
      }
#pragma unroll
      for (int j = 0; j < 2; ++j) {
        int r = wn * 64 + 32 * j + ar;
        int c8 = (ks * 2 + hb) ^ swz32(r);
        bh[j] = *(const bf8_t*)(lb + TILE + r * 32 + c8 * 8);
      }
#pragma unroll
      for (int i = 0; i < 2; ++i)
#pragma unroll
        for (int j = 0; j < 2; ++j)
          acc[i][j] = MFMA32(ah[i], bh[j], acc[i][j]);
    }
    buf ^= 1;
  }
}

// C/D row-within-frag for 32x32: (r&3) + 8*(r>>2) + 4*hb
__device__ __forceinline__ int crow32(int r, int hb) {
  return (r & 3) + 8 * (r >> 2) + 4 * hb;
}

// ---------------------------------------------------------------------------
// Prep: S -> Bcat seg0/seg2 (bf16) + STb transposed bf16 copy
// ---------------------------------------------------------------------------
__global__ __launch_bounds__(256) void stb_k(const float* __restrict__ S,
                                             ushort* __restrict__ Bcat,
                                             ushort* __restrict__ STb) {
  __shared__ float tile[16][17];
  int s = blockIdx.z;
  int n0 = blockIdx.y * 16, m0 = blockIdx.x * 16;
  int tx = threadIdx.x & 15, ty = threadIdx.x >> 4;
  float v = S[(size_t)s * 262144 + (size_t)(n0 + ty) * 512 + m0 + tx];
  tile[ty][tx] = v;
  Bcat[(size_t)(n0 + ty) * 2048 + (size_t)(2 * s) * 512 + m0 + tx] = f2bf(v);
  __syncthreads();
  STb[(size_t)s * 262144 + (size_t)(m0 + ty) * 512 + n0 + tx] = f2bf(tile[tx][ty]);
}

// SS = S^2 via 1-term MFMA: A = Bcat seg(2s) rows (n, lda 2048), B = STb rows (m).
// Writes Bcat seg(2s+1).
__global__ __launch_bounds__(256) void ssqm_k(const ushort* __restrict__ Bc,
                                              const ushort* __restrict__ STb,
                                              ushort* __restrict__ Bout) {
  __shared__ __attribute__((aligned(16))) ushort lds[2 * 2 * 128 * 32];
  int tid = threadIdx.x, lane = tid & 63, wave = tid >> 6;
  int wm = wave >> 1, wn = wave & 1, ar = lane & 31, hb = lane >> 5;
  int a = blockIdx.x, bm = blockIdx.y, s = blockIdx.z;
  f16_t acc[2][2] = {};
  core128_1(Bc + (size_t)(a * 128) * 2048 + (size_t)(2 * s) * 512, 2048,
            STb + (size_t)s * 262144 + (size_t)(bm * 128) * 512, 512,
            512, lds, acc);
#pragma unroll
  for (int i = 0; i < 2; ++i)
#pragma unroll
    for (int j = 0; j < 2; ++j) {
      int m_ = bm * 128 + wn * 64 + 32 * j + ar;
#pragma unroll
      for (int r = 0; r < 16; ++r) {
        int n_ = a * 128 + wm * 64 + 32 * i + crow32(r, hb);
        Bout[(size_t)n_ * 2048 + (size_t)(2 * s + 1) * 512 + m_] = f2bf(acc[i][j][r]);
      }
    }
}

// ---------------------------------------------------------------------------
// One-shot weight prep into packed region. Per-cell layout (ushort offsets):
// [gid_h 16384][gid_l 16384][gd 65536][cid_h 8192][cid_l 8192][cd 32768]
// ---------------------------------------------------------------------------
struct WSrc { const float* wg[4]; const float* wc[4]; };

__global__ __launch_bounds__(256) void wprep_all_k(WSrc src,
                                                   ushort* __restrict__ Wbuf) {
  int idx = blockIdx.x * 256 + threadIdx.x;
  if (idx >= 4 * 147456) return;
  int ci = idx / 147456, r = idx % 147456;
  int C = (ci == 0) ? 66 : (ci == 2) ? 65 : 128;
  const float* WG = src.wg[ci];
  const float* WC = src.wc[ci];
  ushort v;
  if (r < 32768) {                       // gate id hi/lo
    int e = r & 16383, c = e & 127, d = e >> 7;
    float x = (c < C) ? WG[(size_t)c * 128 + d] : 0.f;
    ushort hh = f2bf(x);
    v = (r < 16384) ? hh : f2bf(x - bf2f(hh));
  } else if (r < 98304) {                // gate diff hi
    int e = r - 32768, c = e & 127, i = e >> 7;
    int t = 1 + (i >> 7), d = i & 127;
    v = (c < C) ? f2bf(WG[(size_t)(t * C + c) * 128 + d]) : (ushort)0;
  } else if (r < 114688) {               // cand id hi/lo
    int e = (r - 98304) & 8191, c = e & 127, d = e >> 7;
    float x = (c < C) ? WC[(size_t)c * 64 + d] : 0.f;
    ushort hh = f2bf(x);
    v = (r < 106496) ? hh : f2bf(x - bf2f(hh));
  } else {                               // cand diff hi
    int e = r - 114688, c = e & 127, i = e >> 7;
    int t = 1 + (i >> 6), d = i & 63;
    v = (c < C) ? f2bf(WC[(size_t)(t * C + c) * 64 + d]) : (ushort)0;
  }
  Wbuf[idx] = v;
}

// ---------------------------------------------------------------------------
// Pack zT[(b,n)][c] = [x | h | 0-pad], split hi/lo. hT is [(b,n)][d].
// xmode 0: inputs gather (t); xmode 1: flat [jg]; xmode 2: hT-row layout
// ---------------------------------------------------------------------------
__global__ __launch_bounds__(256) void packzT_k(const float* __restrict__ xsrc,
                                                int xmode, int t, int Cx, int C,
                                                const float* __restrict__ hT,
                                                ushort* __restrict__ Zh,
                                                ushort* __restrict__ Zl) {
  int jg = blockIdx.x * 256 + threadIdx.x;   // b*512 + n
  int b = jg >> 9, n = jg & 511;
  for (int c0 = 0; c0 < 128; c0 += 8) {
    bf8_t vh, vl;
#pragma unroll
    for (int q = 0; q < 8; ++q) {
      int c = c0 + q;
      float v;
      if (c < Cx) {
        if (xmode == 0)      v = xsrc[((size_t)(b * Cx + c) * 512 + n) * 12 + t];
        else if (xmode == 1) v = xsrc[jg];
        else                 v = xsrc[(size_t)jg * 64 + c];
      } else if (c < C) {
        v = hT[(size_t)jg * 64 + (c - Cx)];
      } else {
        v = 0.f;
      }
      ushort hh = f2bf(v);
      vh[q] = (short)hh;
      vl[q] = (short)f2bf(v - bf2f(hh));
    }
    *(bf8_t*)(Zh + (size_t)jg * 128 + c0) = vh;
    *(bf8_t*)(Zl + (size_t)jg * 128 + c0) = vl;
  }
}

// ---------------------------------------------------------------------------
// Combined g1: mt < NMT -> 1-term diffusion rows (bf16 Gh);
// mt == NMT -> 3-term identity rows (f32 G0T).
// MODE 0: DR=128 gate, NMT=4; MODE 1: DR=64 cand, NMT=2.
// ---------------------------------------------------------------------------
template <int MODE>
__global__ __launch_bounds__(256, 2) void g1_k(const ushort* __restrict__ Wih,
                                               const ushort* __restrict__ Wil,
                                               const ushort* __restrict__ Wd,
                                               const ushort* __restrict__ Zh,
                                               const ushort* __restrict__ Zl,
                                               ushort* __restrict__ Gh,
                                               float* __restrict__ G0T, int K) {
  __shared__ __attribute__((aligned(16))) ushort lds[2 * 4 * 128 * 32];
  constexpr int DR = (MODE == 0) ? 128 : 64;
  constexpr int NMT = (MODE == 0) ? 4 : 2;
  int tid = threadIdx.x, lane = tid & 63, wave = tid >> 6;
  int wm = wave >> 1, wn = wave & 1, ar = lane & 31, hb = lane >> 5;
  int L = xcd_logical(256 * (NMT + 1));
  int mt = L % (NMT + 1), nt = L / (NMT + 1);
  f16_t acc[2][2] = {};
  if (mt == NMT) {
    core128(Wih, Wil, 128,
            Zh + (size_t)nt * 128 * 128, Zl + (size_t)nt * 128 * 128, 128,
            K, lds, acc);
#pragma unroll
    for (int i = 0; i < 2; ++i)
#pragma unroll
      for (int j = 0; j < 2; ++j) {
        int jg = nt * 128 + wn * 64 + 32 * j + ar;
#pragma unroll
        for (int r = 0; r < 16; ++r) {
          int d = wm * 64 + 32 * i + crow32(r, hb);
          if (d >= DR) continue;
          G0T[(size_t)jg * DR + d] = acc[i][j][r];
        }
      }
  } else {
    core128_1(Wd + (size_t)mt * 128 * 128, 128,
              Zh + (size_t)nt * 128 * 128, 128,
              K, lds, acc);
#pragma unroll
    for (int i = 0; i < 2; ++i)
#pragma unroll
      for (int j = 0; j < 2; ++j) {
        int jg = nt * 128 + wn * 64 + 32 * j + ar;
        int b = jg >> 9, m = jg & 511;
#pragma unroll
        for (int r = 0; r < 16; ++r) {
          int ii = mt * 128 + wm * 64 + 32 * i + crow32(r, hb);
          int tt = ii / DR, d = ii % DR;
          Gh[((size_t)(b * DR + d)) * 2048 + (size_t)tt * 512 + m] = f2bf(acc[i][j][r]);
        }
      }
  }
}

// ---------------------------------------------------------------------------
// Gate diffusion GEMM (1-term, 2-tile), split-K kz=3 (768/768/512): -> P
// ---------------------------------------------------------------------------
__global__ __launch_bounds__(256, 3) void ru1g_k(const ushort* __restrict__ Gh,
                                                 const ushort* __restrict__ Bch,
                                                 float* __restrict__ P) {
  __shared__ __attribute__((aligned(16))) ushort lds[2 * 2 * 128 * 32];
  int tid = threadIdx.x, lane = tid & 63, wave = tid >> 6;
  int wm = wave >> 1, wn = wave & 1, ar = lane & 31, hb = lane >> 5;
  int L = xcd_logical(768);
  int mt = L & 3, nt = (L >> 2) & 63, kz = L >> 8;   // kz 0..2
  int k0 = kz * 768;
  int K  = (kz == 2) ? 512 : 768;
  f16_t acc[2][2] = {};
  core128_1(Bch + (size_t)mt * 128 * 2048 + k0, 2048,
            Gh + (size_t)nt * 128 * 2048 + k0, 2048,
            K, lds, acc);
  float* Pz = P + (size_t)kz * 4194304;
#pragma unroll
  for (int i = 0; i < 2; ++i)
#pragma unroll
    for (int j = 0; j < 2; ++j) {
      int R = nt * 128 + wn * 64 + 32 * j + ar;
      int b = R >> 7, d = R & 127;
#pragma unroll
      for (int r = 0; r < 16; ++r) {
        int node = mt * 128 + wm * 64 + 32 * i + crow32(r, hb);
        Pz[((size_t)b * 512 + node) * 128 + d] = acc[i][j][r];
      }
    }
}

// finish gate: sigmoid(P0+P1+P2+G0T+bg); d<64 -> r*h into zT; d>=64 -> u into U
__global__ __launch_bounds__(256) void ru1f_k(const float* __restrict__ P,
                                              const float* __restrict__ G0T,
                                              const float* __restrict__ bg,
                                              const float* __restrict__ hT,
                                              float* __restrict__ U,
                                              ushort* __restrict__ Zh,
                                              ushort* __restrict__ Zl, int Cx) {
  int i4 = blockIdx.x * 256 + threadIdx.x;
  if (i4 >= 1048576) return;
  int base = i4 * 4;
  int row = base >> 7, d = base & 127;
  f4v_t p0 = *(const f4v_t*)(P + base);
  f4v_t p1 = *(const f4v_t*)(P + 4194304 + base);
  f4v_t p2 = *(const f4v_t*)(P + 2 * 4194304 + base);
  f4v_t g0 = *(const f4v_t*)(G0T + base);
  if (d < 64) {
    f4v_t hv = *(const f4v_t*)(hT + (size_t)row * 64 + d);
#pragma unroll
    for (int e = 0; e < 4; ++e) {
      float s = 1.f / (1.f + expf(-(p0[e] + p1[e] + p2[e] + g0[e] + bg[d + e])));
      float rh = s * hv[e];
      ushort hh = f2bf(rh);
      Zh[(size_t)row * 128 + Cx + d + e] = hh;
      Zl[(size_t)row * 128 + Cx + d + e] = f2bf(rh - bf2f(hh));
    }
  } else {
    f4v_t uo;
#pragma unroll
    for (int e = 0; e < 4; ++e)
      uo[e] = 1.f / (1.f + expf(-(p0[e] + p1[e] + p2[e] + g0[e] + bg[d + e])));
    *(f4v_t*)(U + (size_t)row * 64 + (d - 64)) = uo;
  }
}

// ---------------------------------------------------------------------------
// Cand diffusion GEMM (1-term, 2-tile), split-K kz=4.
// ---------------------------------------------------------------------------
__global__ __launch_bounds__(256, 3) void ru2g_k(const ushort* __restrict__ Gh,
                                                 const ushort* __restrict__ Bch,
                                                 float* __restrict__ P) {
  __shared__ __attribute__((aligned(16))) ushort lds[2 * 2 * 128 * 32];
  int tid = threadIdx.x, lane = tid & 63, wave = tid >> 6;
  int wm = wave >> 1, wn = wave & 1, ar = lane & 31, hb = lane >> 5;
  int L = xcd_logical(512);
  int mt = L & 3, nt = (L >> 2) & 31, kz = L >> 7;
  f16_t acc[2][2] = {};
  core128_1(Bch + (size_t)mt * 128 * 2048 + kz * 512, 2048,
            Gh + (size_t)nt * 128 * 2048 + kz * 512, 2048,
            512, lds, acc);
  float* Pz = P + (size_t)kz * 2097152;
#pragma unroll
  for (int i = 0; i < 2; ++i)
#pragma unroll
    for (int j = 0; j < 2; ++j) {
      int R = nt * 128 + wn * 64 + 32 * j + ar;
      int b = R >> 6, d = R & 63;
#pragma unroll
      for (int r = 0; r < 16; ++r) {
        int node = mt * 128 + wm * 64 + 32 * i + crow32(r, hb);
        Pz[((size_t)b * 512 + node) * 64 + d] = acc[i][j][r];
      }
    }
}

// finish cand: c~ = tanh(sum P + G0c + bc); h = u*h + (1-u)*c~
__global__ __launch_bounds__(256) void ru2f_k(const float* __restrict__ P,
                                              const float* __restrict__ G0c,
                                              const float* __restrict__ bc,
                                              const float* __restrict__ U,
                                              float* __restrict__ hT) {
  int i4 = blockIdx.x * 256 + threadIdx.x;
  if (i4 >= 524288) return;
  int base = i4 * 4;
  int d = base & 63;
  f4v_t p0 = *(const f4v_t*)(P + base);
  f4v_t p1 = *(const f4v_t*)(P + 2097152 + base);
  f4v_t p2 = *(const f4v_t*)(P + 2 * 2097152 + base);
  f4v_t p3 = *(const f4v_t*)(P + 3 * 2097152 + base);
  f4v_t g0 = *(const f4v_t*)(G0c + base);
  f4v_t uv = *(const f4v_t*)(U + base);
  f4v_t hv = *(const f4v_t*)(hT + base);
#pragma unroll
  for (int e = 0; e < 4; ++e) {
    float ct = tanhf(p0[e] + p1[e] + p2[e] + p3[e] + g0[e] + bc[d + e]);
    hv[e] = uv[e] * hv[e] + (1.f - uv[e]) * ct;
  }
  *(f4v_t*)(hT + base) = hv;
}

__global__ __launch_bounds__(256) void proj_out_k(const float* __restrict__ h1T,
                                                  const float* __restrict__ pw,
                                                  const float* __restrict__ pb,
                                                  float* __restrict__ ybuf,
                                                  float* __restrict__ out, int k) {
  int idx = blockIdx.x * blockDim.x + threadIdx.x;
  if (idx >= B_ * N_) return;
  float s = pb[0];
  const float* hrow = h1T + (size_t)idx * 64;
#pragma unroll
  for (int j = 0; j < 64; ++j)
    s = fmaf(pw[j], hrow[j], s);
  ybuf[idx] = s;
  out[(size_t)idx * 12 + k] = s;
}

extern "C" void kernel_launch(void* const* d_in, const int* in_sizes, int n_in,
                              void* d_out, int out_size, void* d_ws, size_t ws_size,
                              hipStream_t stream) {
  const float* inputs   = (const float*)d_in[0];
  const float* supports = (const float*)d_in[1];
  WSrc wsrc;
  wsrc.wg[0] = (const float*)d_in[2];  wsrc.wg[1] = (const float*)d_in[6];
  wsrc.wg[2] = (const float*)d_in[10]; wsrc.wg[3] = (const float*)d_in[14];
  wsrc.wc[0] = (const float*)d_in[4];  wsrc.wc[1] = (const float*)d_in[8];
  wsrc.wc[2] = (const float*)d_in[12]; wsrc.wc[3] = (const float*)d_in[16];
  const float* Bg[4] = { (const float*)d_in[3],  (const float*)d_in[7],
                         (const float*)d_in[11], (const float*)d_in[15] };
  const float* Bc[4] = { (const float*)d_in[5],  (const float*)d_in[9],
                         (const float*)d_in[13], (const float*)d_in[17] };
  const float* proj_w = (const float*)d_in[18];
  const float* proj_b = (const float*)d_in[19];
  float* out = (float*)d_out;

  char* p = (char*)d_ws;
  auto carve = [&](size_t bytes) { void* q = p; p += (bytes + 255) & ~(size_t)255; return q; };
  ushort* Bch  = (ushort*)carve((size_t)512 * 2048 * 2);
  ushort* zTh  = (ushort*)carve((size_t)32768 * 128 * 2);
  ushort* zTl  = (ushort*)carve((size_t)32768 * 128 * 2);
  ushort* Gh   = (ushort*)carve((size_t)8192 * 2048 * 2);
  float*  G0T  = (float*)carve((size_t)32768 * 128 * 4);
  float*  P    = (float*)carve((size_t)3 * 4194304 * 4);   // 48MB partials
  float*  U    = (float*)carve((size_t)2097152 * 4);
  float*  h0   = (float*)carve((size_t)2097152 * 4);
  float*  h1   = (float*)carve((size_t)2097152 * 4);
  float*  ybuf = (float*)carve((size_t)B_ * N_ * 4);
  ushort* Wbuf = (ushort*)carve((size_t)4 * 147456 * 2);
  ushort* STb  = (ushort*)U;     // overlay: STb (1MB) only needed during prep

  // h0 + h1 + ybuf are contiguous 256B-multiple carves -> one memset
  hipMemsetAsync(h0, 0, (size_t)2097152 * 4 * 2 + (size_t)B_ * N_ * 4, stream);

  stb_k<<<dim3(32, 32, 2), 256, 0, stream>>>(supports, Bch, STb);
  ssqm_k<<<dim3(4, 4, 2), 256, 0, stream>>>(Bch, STb, Bch);
  wprep_all_k<<<(4 * 147456 + 255) / 256, 256, 0, stream>>>(wsrc, Wbuf);

  auto cell = [&](int ci, int Cx, const float* x, int xmode, int t, float* h) {
    int C = Cx + 64;
    int K1 = (C + 31) & ~31;   // 96 or 128
    ushort* cw = Wbuf + (size_t)ci * 147456;
    ushort* Wgid_h = cw;          ushort* Wgid_l = cw + 16384;
    ushort* Wgd    = cw + 32768;
    ushort* Wcid_h = cw + 98304;  ushort* Wcid_l = cw + 106496;
    ushort* Wcd    = cw + 114688;
    packzT_k<<<128, 256, 0, stream>>>(x, xmode, t, Cx, C, h, zTh, zTl);
    g1_k<0><<<dim3(256, 5), 256, 0, stream>>>(Wgid_h, Wgid_l, Wgd, zTh, zTl, Gh, G0T, K1);
    ru1g_k<<<dim3(64, 4, 3), 256, 0, stream>>>(Gh, Bch, P);
    ru1f_k<<<4096, 256, 0, stream>>>(P, G0T, Bg[ci], h, U, zTh, zTl, Cx);
    g1_k<1><<<dim3(256, 3), 256, 0, stream>>>(Wcid_h, Wcid_l, Wcd, zTh, zTl, Gh, G0T, K1);
    ru2g_k<<<dim3(32, 4, 4), 256, 0, stream>>>(Gh, Bch, P);
    ru2f_k<<<2048, 256, 0, stream>>>(P, G0T, Bc[ci], U, h);
  };

  for (int t = 0; t < 12; ++t) {
    cell(0, 2, inputs, 0, t, h0);
    cell(1, 64, h0, 2, 0, h1);
  }
  for (int k = 0; k < 12; ++k) {
    cell(2, 1, ybuf, 1, 0, h0);
    cell(3, 64, h0, 2, 0, h1);
    proj_out_k<<<(B_ * N_ + 255) / 256, 256, 0, stream>>>(h1, proj_w, proj_b, ybuf, out, k);
  }
}